// Round 2
// baseline (2785.173 us; speedup 1.0000x reference)
//
#include <hip/hip_runtime.h>
#include <math.h>

#define Bv 2
#define Lv 1024
#define Hv 16
#define Dv 64
#define HIDv 1024

typedef unsigned short u16;
typedef short bf16x8 __attribute__((ext_vector_type(8)));
typedef float f32x4 __attribute__((ext_vector_type(4)));

__device__ __forceinline__ u16 f2b(float f) {
    union { float f; unsigned u; } v; v.f = f;
    unsigned r = v.u + 0x7fffu + ((v.u >> 16) & 1u);
    return (u16)(r >> 16);
}
__device__ __forceinline__ float b2f(u16 h) {
    union { unsigned u; float f; } v; v.u = ((unsigned)h) << 16;
    return v.f;
}

// ---------------------------------------------------------------------------
// bf16 MFMA GEMM: C = alpha * A @ B^T
// A: MxK bf16 row-major; B: NxK bf16 row-major (i.e. B^T layout); C: MxN.
// 256 threads = 4 waves; block tile BM x BN; wave tile WM x WN.
// tri_skip: skip blocks with n0 > m0 (causal upper tiles).
// tri_k:    bound K-loop at m0+BM (causal PV).
// ---------------------------------------------------------------------------
template<int BM, int BN, int WM, int WN, bool CBF16>
__global__ __launch_bounds__(256) void gemm_bt(
    const u16* __restrict__ A, const u16* __restrict__ B, void* __restrict__ Cv,
    int M, int N, int K, long long sA, long long sB, long long sC,
    float alpha, int tri_skip, int tri_k)
{
    constexpr int NW = BN / WN;          // waves along N
    constexpr int MI = WM / 16;
    constexpr int NI = WN / 16;
    constexpr int LDT = 40;              // padded LDS row (bf16 elems): 80B stride
    __shared__ u16 As[BM * LDT];
    __shared__ u16 Bs[BN * LDT];

    const int m0 = blockIdx.y * BM;
    const int n0 = blockIdx.x * BN;
    if (tri_skip && n0 > m0) return;
    A += (long long)blockIdx.z * sA;
    B += (long long)blockIdx.z * sB;

    const int tid = threadIdx.x;
    const int lane = tid & 63;
    const int wave = tid >> 6;
    const int wm0 = (wave / NW) * WM;
    const int wn0 = (wave % NW) * WN;
    const int fr = lane & 15;            // fragment row (m or n)
    const int fq = lane >> 4;            // quad -> k chunk

    f32x4 acc[MI][NI];
    #pragma unroll
    for (int i = 0; i < MI; ++i)
        #pragma unroll
        for (int j = 0; j < NI; ++j) acc[i][j] = (f32x4){0.f, 0.f, 0.f, 0.f};

    int Kend = K;
    if (tri_k) { int kb = m0 + BM; if (kb < Kend) Kend = kb; }

    for (int k0 = 0; k0 < Kend; k0 += 32) {
        #pragma unroll
        for (int c = 0; c < (BM * 4) / 256; ++c) {
            int cid = tid + c * 256;
            int r = cid >> 2, ks = (cid & 3) * 8;
            *(bf16x8*)&As[r * LDT + ks] =
                *(const bf16x8*)(A + (long long)(m0 + r) * K + k0 + ks);
        }
        #pragma unroll
        for (int c = 0; c < (BN * 4) / 256; ++c) {
            int cid = tid + c * 256;
            int r = cid >> 2, ks = (cid & 3) * 8;
            *(bf16x8*)&Bs[r * LDT + ks] =
                *(const bf16x8*)(B + (long long)(n0 + r) * K + k0 + ks);
        }
        __syncthreads();
        bf16x8 af[MI], bfr[NI];
        #pragma unroll
        for (int i = 0; i < MI; ++i)
            af[i] = *(const bf16x8*)&As[(wm0 + i * 16 + fr) * LDT + fq * 8];
        #pragma unroll
        for (int j = 0; j < NI; ++j)
            bfr[j] = *(const bf16x8*)&Bs[(wn0 + j * 16 + fr) * LDT + fq * 8];
        #pragma unroll
        for (int i = 0; i < MI; ++i)
            #pragma unroll
            for (int j = 0; j < NI; ++j)
                acc[i][j] = __builtin_amdgcn_mfma_f32_16x16x32_bf16(
                    af[i], bfr[j], acc[i][j], 0, 0, 0);
        __syncthreads();
    }

    const long long cb = (long long)blockIdx.z * sC;
    #pragma unroll
    for (int i = 0; i < MI; ++i)
        #pragma unroll
        for (int j = 0; j < NI; ++j)
            #pragma unroll
            for (int r = 0; r < 4; ++r) {
                int row = m0 + wm0 + i * 16 + fq * 4 + r;
                int col = n0 + wn0 + j * 16 + fr;
                float v = acc[i][j][r] * alpha;
                if (CBF16) ((u16*)Cv)[cb + (long long)row * N + col] = f2b(v);
                else      ((float*)Cv)[cb + (long long)row * N + col] = v;
            }
}

// ---------------------------------------------------------------------------
// fp32 -> bf16 elementwise cast
// ---------------------------------------------------------------------------
__global__ __launch_bounds__(256) void cast_f2b(
    const float* __restrict__ src, u16* __restrict__ dst, int n)
{
    int i = blockIdx.x * 256 + threadIdx.x;
    if (i < n) dst[i] = f2b(src[i]);
}

// ---------------------------------------------------------------------------
// dst[n][m] = bf16(src[m][n]); grid (N/64, M/64), 256 threads
// ---------------------------------------------------------------------------
__global__ __launch_bounds__(256) void transpose_cast_f2b(
    const float* __restrict__ src, u16* __restrict__ dst, int M, int N)
{
    __shared__ float tile[64][65];
    const int m0 = blockIdx.y * 64, n0 = blockIdx.x * 64;
    const int tid = threadIdx.x;
    #pragma unroll
    for (int c = 0; c < 4; ++c) {
        int f = tid + c * 256;
        int r = f >> 4, cs = (f & 15) * 4;
        float4 v = *(const float4*)&src[(long long)(m0 + r) * N + n0 + cs];
        tile[r][cs] = v.x; tile[r][cs + 1] = v.y;
        tile[r][cs + 2] = v.z; tile[r][cs + 3] = v.w;
    }
    __syncthreads();
    int nl = tid >> 2, ms = (tid & 3) * 16;
    u16 outv[16];
    #pragma unroll
    for (int c = 0; c < 16; ++c) outv[c] = f2b(tile[ms + c][nl]);
    *(bf16x8*)&dst[(long long)(n0 + nl) * M + m0 + ms]     = *(bf16x8*)&outv[0];
    *(bf16x8*)&dst[(long long)(n0 + nl) * M + m0 + ms + 8] = *(bf16x8*)&outv[8];
}

// ---------------------------------------------------------------------------
// v (bh)[1024][64] bf16 -> vT (bh)[64][1024] bf16; grid (16, B*H)
// ---------------------------------------------------------------------------
__global__ __launch_bounds__(256) void vtrans(
    const u16* __restrict__ src, u16* __restrict__ dst)
{
    __shared__ u16 tile[64][65];
    const int bh = blockIdx.y;
    const int l0 = blockIdx.x * 64;
    const int tid = threadIdx.x;
    const u16* s = src + (long long)bh * 65536;
    u16* d = dst + (long long)bh * 65536;
    #pragma unroll
    for (int c = 0; c < 2; ++c) {
        int f = tid + c * 256;
        int r = f >> 3, cs = (f & 7) * 8;
        bf16x8 v = *(const bf16x8*)&s[(l0 + r) * 64 + cs];
        #pragma unroll
        for (int e = 0; e < 8; ++e) tile[r][cs + e] = (u16)v[e];
    }
    __syncthreads();
    int dl = tid >> 2, ls = (tid & 3) * 16;
    u16 outv[16];
    #pragma unroll
    for (int c = 0; c < 16; ++c) outv[c] = tile[ls + c][dl];
    *(bf16x8*)&d[dl * 1024 + l0 + ls]     = *(bf16x8*)&outv[0];
    *(bf16x8*)&d[dl * 1024 + l0 + ls + 8] = *(bf16x8*)&outv[8];
}

// ---------------------------------------------------------------------------
// RoPE + split qkv(B,L,3,H,D) fp32 -> q,k,v (B,H,L,D) bf16
// ---------------------------------------------------------------------------
__global__ __launch_bounds__(256) void rope_split_bf(
    const float* __restrict__ qkv,
    u16* __restrict__ q, u16* __restrict__ k, u16* __restrict__ v)
{
    int idx = blockIdx.x * 256 + threadIdx.x;
    int d = idx & 63;
    int l = (idx >> 6) & 1023;
    int h = (idx >> 16) & 15;
    int b = idx >> 20;
    const long long src = ((long long)(b * Lv + l) * 3) * 1024 + h * 64 + d;
    int i = d & 31;
    float inv_freq = __expf((float)i * -0.28782313662425574f); // -ln(10000)/32
    float arg = (float)l * inv_freq;
    float c, s;
    __sincosf(arg, &s, &c);
    float x0 = qkv[src];
    float xr0 = (d < 32) ? -qkv[src + 32] : qkv[src - 32];
    q[idx] = f2b(x0 * c + xr0 * s);
    float x1 = qkv[src + 1024];
    float xr1 = (d < 32) ? -qkv[src + 1024 + 32] : qkv[src + 1024 - 32];
    k[idx] = f2b(x1 * c + xr1 * s);
    v[idx] = f2b(qkv[src + 2048]);
}

// ---------------------------------------------------------------------------
// Fused kerple + DAPE MLP + causal mask + softmax, IN-PLACE on bf16 scores.
// One block per (b, i): reads raw scores (j<=i), writes softmax weights
// (bf16) with zeros padded up to the next 128 boundary (for triangular PV).
// 2 positions per thread per pass; weights via broadcast b128 LDS reads.
// ---------------------------------------------------------------------------
__global__ __launch_bounds__(256) void dape_softmax(
    u16* __restrict__ S,
    const float* __restrict__ log_p, const float* __restrict__ log_a,
    const float* __restrict__ w1, const float* __restrict__ b1,
    const float* __restrict__ w2, const float* __restrict__ b2)
{
    __shared__ u16 sc[16 * 1024];        // final logits, bf16
    __shared__ float sw1t[32 * 36];      // w1T[o][c], padded for b128
    __shared__ float sw2[32 * 16];       // w2[o][h]
    __shared__ float sb1[32], sp[16], sa[16], sb2v[16];
    __shared__ float red[16 * 17];
    __shared__ float rmax[16], rsum[16];

    const int tid = threadIdx.x;
    const int i = 1023 - blockIdx.x;     // longest rows scheduled first
    const int b = blockIdx.y;

    for (int t = tid; t < 1024; t += 256) sw1t[(t & 31) * 36 + (t >> 5)] = w1[t];
    for (int t = tid; t < 512;  t += 256) sw2[t] = w2[t];
    if (tid < 32) sb1[tid] = b1[tid];
    if (tid < 16) {
        sb2v[tid] = b2[tid];
        sp[tid] = log1pf(__expf(log_p[tid]));
        sa[tid] = log1pf(__expf(log_a[tid]));
    }
    __syncthreads();

    const long long base = (long long)b * 16 * 1048576 + (long long)i * 1024;

    #pragma unroll
    for (int pass = 0; pass < 2; ++pass) {
        const int j0 = tid + pass * 512;
        const int j1 = j0 + 256;
        const bool a0 = j0 <= i, a1 = j1 <= i;
        if (!(a0 || a1)) continue;       // no barrier inside: safe
        float comb0[32], comb1[32];
        #pragma unroll
        for (int h = 0; h < 16; ++h) {
            comb0[h] = a0 ? b2f(S[base + (long long)h * 1048576 + j0]) : 0.f;
            comb1[h] = a1 ? b2f(S[base + (long long)h * 1048576 + j1]) : 0.f;
        }
        float d0 = a0 ? (float)(i - j0) : 0.f;
        float d1 = a1 ? (float)(i - j1) : 0.f;
        #pragma unroll
        for (int h = 0; h < 16; ++h) {
            comb0[16 + h] = -sp[h] * log1pf(sa[h] * d0);
            comb1[16 + h] = -sp[h] * log1pf(sa[h] * d1);
        }
        float out0[16], out1[16];
        #pragma unroll
        for (int h = 0; h < 16; ++h) { out0[h] = sb2v[h]; out1[h] = sb2v[h]; }
        #pragma unroll
        for (int o = 0; o < 32; ++o) {
            float ac0 = sb1[o], ac1 = sb1[o];
            #pragma unroll
            for (int c4 = 0; c4 < 8; ++c4) {
                float4 w = *(const float4*)&sw1t[o * 36 + c4 * 4];
                ac0 += comb0[c4*4+0]*w.x + comb0[c4*4+1]*w.y + comb0[c4*4+2]*w.z + comb0[c4*4+3]*w.w;
                ac1 += comb1[c4*4+0]*w.x + comb1[c4*4+1]*w.y + comb1[c4*4+2]*w.z + comb1[c4*4+3]*w.w;
            }
            float g0 = 0.5f * ac0 * (1.f + erff(ac0 * 0.70710678118654752f));
            float g1 = 0.5f * ac1 * (1.f + erff(ac1 * 0.70710678118654752f));
            #pragma unroll
            for (int h4 = 0; h4 < 4; ++h4) {
                float4 w = *(const float4*)&sw2[o * 16 + h4 * 4];
                out0[h4*4+0] += g0*w.x; out0[h4*4+1] += g0*w.y;
                out0[h4*4+2] += g0*w.z; out0[h4*4+3] += g0*w.w;
                out1[h4*4+0] += g1*w.x; out1[h4*4+1] += g1*w.y;
                out1[h4*4+2] += g1*w.z; out1[h4*4+3] += g1*w.w;
            }
        }
        if (a0) {
            #pragma unroll
            for (int h = 0; h < 16; ++h)
                sc[h * 1024 + j0] = f2b(comb0[h] + comb0[16 + h] + out0[h]);
        }
        if (a1) {
            #pragma unroll
            for (int h = 0; h < 16; ++h)
                sc[h * 1024 + j1] = f2b(comb1[h] + comb1[16 + h] + out1[h]);
        }
    }
    __syncthreads();

    // softmax: 16 groups of 16 threads, one head each
    const int jc = i + 1;
    const int h = tid >> 4, lg = tid & 15;
    float mx = -3.0e38f;
    for (int j = lg; j < jc; j += 16) mx = fmaxf(mx, b2f(sc[h * 1024 + j]));
    red[h * 17 + lg] = mx;
    __syncthreads();
    if (lg == 0) {
        float m2 = red[h * 17];
        #pragma unroll
        for (int t = 1; t < 16; ++t) m2 = fmaxf(m2, red[h * 17 + t]);
        rmax[h] = m2;
    }
    __syncthreads();
    float sm = 0.f;
    {
        const float m2 = rmax[h];
        for (int j = lg; j < jc; j += 16) sm += __expf(b2f(sc[h * 1024 + j]) - m2);
    }
    red[h * 17 + lg] = sm;
    __syncthreads();
    if (lg == 0) {
        float s2 = 0.f;
        #pragma unroll
        for (int t = 0; t < 16; ++t) s2 += red[h * 17 + t];
        rsum[h] = s2;
    }
    __syncthreads();

    const int we = ((i >> 7) + 1) << 7;  // zero wedge up to PV's K bound
    for (int h2 = 0; h2 < 16; ++h2) {
        const float m2 = rmax[h2];
        const float inv = 1.0f / rsum[h2];
        for (int j = tid; j < we; j += 256) {
            float v = (j <= i) ? __expf(b2f(sc[h2 * 1024 + j]) - m2) * inv : 0.f;
            S[base + (long long)h2 * 1048576 + j] = f2b(v);
        }
    }
}

// ---------------------------------------------------------------------------
// (B,H,L,D) fp32 -> (B,L,H*D) bf16
// ---------------------------------------------------------------------------
__global__ __launch_bounds__(256) void transpose_out_bf(
    const float* __restrict__ src, u16* __restrict__ dst)
{
    int idx = blockIdx.x * 256 + threadIdx.x;
    int d = idx & 63, h = (idx >> 6) & 15, l = (idx >> 10) & 1023, b = idx >> 20;
    dst[idx] = f2b(src[(((long long)(b * 16 + h)) * 1024 + l) * 64 + d]);
}

// ---------------------------------------------------------------------------
extern "C" void kernel_launch(void* const* d_in, const int* in_sizes, int n_in,
                              void* d_out, int out_size, void* d_ws, size_t ws_size,
                              hipStream_t stream)
{
    const float* x     = (const float*)d_in[0];
    const float* w_qkv = (const float*)d_in[1];
    const float* w_o   = (const float*)d_in[2];
    const float* log_p = (const float*)d_in[3];
    const float* log_a = (const float*)d_in[4];
    const float* w1    = (const float*)d_in[5];
    const float* b1    = (const float*)d_in[6];
    const float* w2    = (const float*)d_in[7];
    const float* b2    = (const float*)d_in[8];
    float* out = (float*)d_out;

    char* p = (char*)d_ws;
    float* qkv   = (float*)p;  p += 6291456ll * 4;   // (B,L,3,H,D) fp32
    u16* x_bf    = (u16*)p;    p += 2097152ll * 2;
    u16* wqkvT   = (u16*)p;    p += 3145728ll * 2;   // (3HD, HID)
    u16* woT     = (u16*)p;    p += 1048576ll * 2;   // (HID, HD)
    u16* q_bf    = (u16*)p;    p += 2097152ll * 2;   // (B,H,L,D)
    u16* k_bf    = (u16*)p;    p += 2097152ll * 2;
    u16* v_bf    = (u16*)p;    p += 2097152ll * 2;
    u16* vT      = (u16*)p;    p += 2097152ll * 2;   // (B,H,D,L)
    u16* scores  = (u16*)p;    p += 33554432ll * 2;  // (B,H,L,L) bf16, in-place weights
    float* attn  = (float*)p;  p += 2097152ll * 4;   // (B,H,L,D) fp32
    u16* attn_bf = (u16*)p;    p += 2097152ll * 2;   // (B,L,H*D)

    // casts / transposes of inputs (cheap, every call)
    cast_f2b<<<8192, 256, 0, stream>>>(x, x_bf, 2097152);
    transpose_cast_f2b<<<dim3(48, 16), 256, 0, stream>>>(w_qkv, wqkvT, HIDv, 3 * Hv * Dv);
    transpose_cast_f2b<<<dim3(16, 16), 256, 0, stream>>>(w_o, woT, Hv * Dv, HIDv);

    // 1. qkv = x @ w_qkv   (2048 x 3072 x 1024)
    gemm_bt<128, 128, 64, 64, false><<<dim3(24, 16, 1), 256, 0, stream>>>(
        x_bf, wqkvT, qkv, 2048, 3072, 1024, 0, 0, 0, 1.0f, 0, 0);

    // 2. rope + split -> bf16
    rope_split_bf<<<8192, 256, 0, stream>>>(qkv, q_bf, k_bf, v_bf);
    vtrans<<<dim3(16, 32), 256, 0, stream>>>(v_bf, vT);

    // 3. scores = (q @ k^T)/8, causal tiles only, bf16 out
    gemm_bt<128, 128, 64, 64, true><<<dim3(8, 8, 32), 256, 0, stream>>>(
        q_bf, k_bf, scores, 1024, 1024, 64,
        65536, 65536, 1048576, 0.125f, 1, 0);

    // 4. kerple + DAPE MLP + causal + softmax (in-place)
    dape_softmax<<<dim3(1024, 2), 256, 0, stream>>>(
        scores, log_p, log_a, w1, b1, w2, b2);

    // 5. attn = weights @ v  (triangular K)
    gemm_bt<128, 64, 64, 32, false><<<dim3(1, 8, 32), 256, 0, stream>>>(
        scores, vT, attn, 1024, 64, 1024,
        1048576, 65536, 65536, 1.0f, 0, 1);

    // 6. (B,H,L,D) -> (B,L,H*D) bf16
    transpose_out_bf<<<8192, 256, 0, stream>>>(attn, attn_bf);

    // 7. out = attn_fl @ w_o  (2048 x 1024 x 1024)
    gemm_bt<128, 128, 64, 64, false><<<dim3(8, 16, 1), 256, 0, stream>>>(
        attn_bf, woT, out, 2048, 1024, 1024, 0, 0, 0, 1.0f, 0, 0);
}

// Round 3
// 488.849 us; speedup vs baseline: 5.6974x; 5.6974x over previous
//
#include <hip/hip_runtime.h>
#include <math.h>

#define Bv 2
#define Lv 1024
#define Hv 16
#define Dv 64
#define HIDv 1024

typedef unsigned short u16;
typedef short bf16x8 __attribute__((ext_vector_type(8)));
typedef float f32x4 __attribute__((ext_vector_type(4)));

__device__ __forceinline__ u16 f2b(float f) {
    union { float f; unsigned u; } v; v.f = f;
    unsigned r = v.u + 0x7fffu + ((v.u >> 16) & 1u);
    return (u16)(r >> 16);
}
__device__ __forceinline__ float b2f(u16 h) {
    union { unsigned u; float f; } v; v.u = ((unsigned)h) << 16;
    return v.f;
}

// ---------------------------------------------------------------------------
// bf16 MFMA GEMM: C = alpha * A @ B^T
// A: MxK bf16 row-major; B: NxK bf16 row-major (i.e. B^T layout); C: MxN.
// 256 threads = 4 waves; block tile BM x BN; wave tile WM x WN.
// tri_skip: skip blocks with n0 > m0 (causal upper tiles).
// tri_k:    bound K-loop at m0+BM (causal PV).
// ---------------------------------------------------------------------------
template<int BM, int BN, int WM, int WN, bool CBF16>
__global__ __launch_bounds__(256) void gemm_bt(
    const u16* __restrict__ A, const u16* __restrict__ B, void* __restrict__ Cv,
    int M, int N, int K, long long sA, long long sB, long long sC,
    float alpha, int tri_skip, int tri_k)
{
    constexpr int NW = BN / WN;          // waves along N
    constexpr int MI = WM / 16;
    constexpr int NI = WN / 16;
    constexpr int LDT = 40;              // padded LDS row (bf16 elems): 80B stride
    __shared__ u16 As[BM * LDT];
    __shared__ u16 Bs[BN * LDT];

    const int m0 = blockIdx.y * BM;
    const int n0 = blockIdx.x * BN;
    if (tri_skip && n0 > m0) return;
    A += (long long)blockIdx.z * sA;
    B += (long long)blockIdx.z * sB;

    const int tid = threadIdx.x;
    const int lane = tid & 63;
    const int wave = tid >> 6;
    const int wm0 = (wave / NW) * WM;
    const int wn0 = (wave % NW) * WN;
    const int fr = lane & 15;            // fragment row (m or n)
    const int fq = lane >> 4;            // quad -> k chunk

    f32x4 acc[MI][NI];
    #pragma unroll
    for (int i = 0; i < MI; ++i)
        #pragma unroll
        for (int j = 0; j < NI; ++j) acc[i][j] = (f32x4){0.f, 0.f, 0.f, 0.f};

    int Kend = K;
    if (tri_k) { int kb = m0 + BM; if (kb < Kend) Kend = kb; }

    for (int k0 = 0; k0 < Kend; k0 += 32) {
        #pragma unroll
        for (int c = 0; c < (BM * 4) / 256; ++c) {
            int cid = tid + c * 256;
            int r = cid >> 2, ks = (cid & 3) * 8;
            *(bf16x8*)&As[r * LDT + ks] =
                *(const bf16x8*)(A + (long long)(m0 + r) * K + k0 + ks);
        }
        #pragma unroll
        for (int c = 0; c < (BN * 4) / 256; ++c) {
            int cid = tid + c * 256;
            int r = cid >> 2, ks = (cid & 3) * 8;
            *(bf16x8*)&Bs[r * LDT + ks] =
                *(const bf16x8*)(B + (long long)(n0 + r) * K + k0 + ks);
        }
        __syncthreads();
        bf16x8 af[MI], bfr[NI];
        #pragma unroll
        for (int i = 0; i < MI; ++i)
            af[i] = *(const bf16x8*)&As[(wm0 + i * 16 + fr) * LDT + fq * 8];
        #pragma unroll
        for (int j = 0; j < NI; ++j)
            bfr[j] = *(const bf16x8*)&Bs[(wn0 + j * 16 + fr) * LDT + fq * 8];
        #pragma unroll
        for (int i = 0; i < MI; ++i)
            #pragma unroll
            for (int j = 0; j < NI; ++j)
                acc[i][j] = __builtin_amdgcn_mfma_f32_16x16x32_bf16(
                    af[i], bfr[j], acc[i][j], 0, 0, 0);
        __syncthreads();
    }

    const long long cb = (long long)blockIdx.z * sC;
    #pragma unroll
    for (int i = 0; i < MI; ++i)
        #pragma unroll
        for (int j = 0; j < NI; ++j)
            #pragma unroll
            for (int r = 0; r < 4; ++r) {
                int row = m0 + wm0 + i * 16 + fq * 4 + r;
                int col = n0 + wn0 + j * 16 + fr;
                float v = acc[i][j][r] * alpha;
                if (CBF16) ((u16*)Cv)[cb + (long long)row * N + col] = f2b(v);
                else      ((float*)Cv)[cb + (long long)row * N + col] = v;
            }
}

// ---------------------------------------------------------------------------
// fp32 -> bf16 elementwise cast
// ---------------------------------------------------------------------------
__global__ __launch_bounds__(256) void cast_f2b(
    const float* __restrict__ src, u16* __restrict__ dst, int n)
{
    int i = blockIdx.x * 256 + threadIdx.x;
    if (i < n) dst[i] = f2b(src[i]);
}

// ---------------------------------------------------------------------------
// dst[n][m] = bf16(src[m][n]); grid (N/64, M/64), 256 threads
// ---------------------------------------------------------------------------
__global__ __launch_bounds__(256) void transpose_cast_f2b(
    const float* __restrict__ src, u16* __restrict__ dst, int M, int N)
{
    __shared__ float tile[64][65];
    const int m0 = blockIdx.y * 64, n0 = blockIdx.x * 64;
    const int tid = threadIdx.x;
    #pragma unroll
    for (int c = 0; c < 4; ++c) {
        int f = tid + c * 256;
        int r = f >> 4, cs = (f & 15) * 4;
        float4 v = *(const float4*)&src[(long long)(m0 + r) * N + n0 + cs];
        tile[r][cs] = v.x; tile[r][cs + 1] = v.y;
        tile[r][cs + 2] = v.z; tile[r][cs + 3] = v.w;
    }
    __syncthreads();
    int nl = tid >> 2, ms = (tid & 3) * 16;
    u16 outv[16];
    #pragma unroll
    for (int c = 0; c < 16; ++c) outv[c] = f2b(tile[ms + c][nl]);
    *(bf16x8*)&dst[(long long)(n0 + nl) * M + m0 + ms]     = *(bf16x8*)&outv[0];
    *(bf16x8*)&dst[(long long)(n0 + nl) * M + m0 + ms + 8] = *(bf16x8*)&outv[8];
}

// ---------------------------------------------------------------------------
// v (bh)[1024][64] bf16 -> vT (bh)[64][1024] bf16; grid (16, B*H)
// ---------------------------------------------------------------------------
__global__ __launch_bounds__(256) void vtrans(
    const u16* __restrict__ src, u16* __restrict__ dst)
{
    __shared__ u16 tile[64][65];
    const int bh = blockIdx.y;
    const int l0 = blockIdx.x * 64;
    const int tid = threadIdx.x;
    const u16* s = src + (long long)bh * 65536;
    u16* d = dst + (long long)bh * 65536;
    #pragma unroll
    for (int c = 0; c < 2; ++c) {
        int f = tid + c * 256;
        int r = f >> 3, cs = (f & 7) * 8;
        bf16x8 v = *(const bf16x8*)&s[(l0 + r) * 64 + cs];
        #pragma unroll
        for (int e = 0; e < 8; ++e) tile[r][cs + e] = (u16)v[e];
    }
    __syncthreads();
    int dl = tid >> 2, ls = (tid & 3) * 16;
    u16 outv[16];
    #pragma unroll
    for (int c = 0; c < 16; ++c) outv[c] = tile[ls + c][dl];
    *(bf16x8*)&d[dl * 1024 + l0 + ls]     = *(bf16x8*)&outv[0];
    *(bf16x8*)&d[dl * 1024 + l0 + ls + 8] = *(bf16x8*)&outv[8];
}

// ---------------------------------------------------------------------------
// RoPE + split qkv(B,L,3,H,D) fp32 -> q,k,v (B,H,L,D) bf16
// ---------------------------------------------------------------------------
__global__ __launch_bounds__(256) void rope_split_bf(
    const float* __restrict__ qkv,
    u16* __restrict__ q, u16* __restrict__ k, u16* __restrict__ v)
{
    int idx = blockIdx.x * 256 + threadIdx.x;
    int d = idx & 63;
    int l = (idx >> 6) & 1023;
    int h = (idx >> 16) & 15;
    int b = idx >> 20;
    const long long src = ((long long)(b * Lv + l) * 3) * 1024 + h * 64 + d;
    int i = d & 31;
    float inv_freq = __expf((float)i * -0.28782313662425574f); // -ln(10000)/32
    float arg = (float)l * inv_freq;
    float c, s;
    __sincosf(arg, &s, &c);
    float x0 = qkv[src];
    float xr0 = (d < 32) ? -qkv[src + 32] : qkv[src - 32];
    q[idx] = f2b(x0 * c + xr0 * s);
    float x1 = qkv[src + 1024];
    float xr1 = (d < 32) ? -qkv[src + 1024 + 32] : qkv[src + 1024 - 32];
    k[idx] = f2b(x1 * c + xr1 * s);
    v[idx] = f2b(qkv[src + 2048]);
}

// ---------------------------------------------------------------------------
// Kerple + DAPE MLP, in-place on bf16 scores (B,H,L,L). Lower triangle only.
// One position per thread (low VGPR pressure — the round-2 fused version
// spilled at 256 VGPRs and pushed 4.4 GB of scratch traffic).
// grid: (L/256, L, B); blocks fully above the diagonal exit immediately.
// ---------------------------------------------------------------------------
__global__ __launch_bounds__(256) void dape_mlp2(
    u16* __restrict__ S,
    const float* __restrict__ log_p, const float* __restrict__ log_a,
    const float* __restrict__ w1, const float* __restrict__ b1,
    const float* __restrict__ w2, const float* __restrict__ b2)
{
    const int i = blockIdx.y;
    if ((int)blockIdx.x * 256 > i) return;   // uniform early-exit

    __shared__ float sw1t[32 * 36];      // w1T[o][c], padded to 36 for b128 align
    __shared__ float sw2[32 * 16];       // w2[o][h]
    __shared__ float sb1[32], sp[16], sa[16], sb2v[16];
    const int tid = threadIdx.x;
    for (int t = tid; t < 1024; t += 256) sw1t[(t & 31) * 36 + (t >> 5)] = w1[t];
    for (int t = tid; t < 512;  t += 256) sw2[t] = w2[t];
    if (tid < 32) sb1[tid] = b1[tid];
    if (tid < 16) {
        sb2v[tid] = b2[tid];
        sp[tid] = log1pf(__expf(log_p[tid]));  // softplus
        sa[tid] = log1pf(__expf(log_a[tid]));
    }
    __syncthreads();

    const int j = blockIdx.x * 256 + tid;
    if (j > i) return;
    const int b = blockIdx.z;
    const long long base = (long long)b * 16 * 1048576 + (long long)i * 1024 + j;

    float comb[32];
    #pragma unroll
    for (int h = 0; h < 16; ++h)
        comb[h] = b2f(S[base + (long long)h * 1048576]);
    const float dist = (float)(i - j);
    #pragma unroll
    for (int h = 0; h < 16; ++h)
        comb[16 + h] = -sp[h] * log1pf(sa[h] * dist);

    float out[16];
    #pragma unroll
    for (int h = 0; h < 16; ++h) out[h] = sb2v[h];

    #pragma unroll 8
    for (int o = 0; o < 32; ++o) {
        float ac = sb1[o];
        #pragma unroll
        for (int c4 = 0; c4 < 8; ++c4) {
            float4 w = *(const float4*)&sw1t[o * 36 + c4 * 4];
            ac += comb[c4*4+0]*w.x + comb[c4*4+1]*w.y + comb[c4*4+2]*w.z + comb[c4*4+3]*w.w;
        }
        float g = 0.5f * ac * (1.f + erff(ac * 0.70710678118654752f));
        #pragma unroll
        for (int h4 = 0; h4 < 4; ++h4) {
            float4 w = *(const float4*)&sw2[o * 16 + h4 * 4];
            out[h4*4+0] += g*w.x; out[h4*4+1] += g*w.y;
            out[h4*4+2] += g*w.z; out[h4*4+3] += g*w.w;
        }
    }

    #pragma unroll
    for (int h = 0; h < 16; ++h)
        S[base + (long long)h * 1048576] = f2b(comb[h] + comb[16 + h] + out[h]);
}

// ---------------------------------------------------------------------------
// Row softmax on bf16 logits, in-place -> bf16 weights.
// One block per (b,h,i) row; masks j>i; zero-fills the wedge up to the next
// 128 boundary (the triangular PV GEMM reads K up to m0+128).
// ---------------------------------------------------------------------------
__global__ __launch_bounds__(256) void softmax_bf(u16* __restrict__ S)
{
    const long long r = blockIdx.x;          // (b*16 + h)*1024 + i
    const int i = (int)(r & 1023);
    u16* row = S + r * 1024;
    const int t = threadIdx.x;
    __shared__ float red[256];

    float v0 = (t       <= i) ? b2f(row[t])       : -3.0e38f;
    float v1 = (t + 256 <= i) ? b2f(row[t + 256]) : -3.0e38f;
    float v2 = (t + 512 <= i) ? b2f(row[t + 512]) : -3.0e38f;
    float v3 = (t + 768 <= i) ? b2f(row[t + 768]) : -3.0e38f;
    float m = fmaxf(fmaxf(v0, v1), fmaxf(v2, v3));
    red[t] = m;
    __syncthreads();
    for (int off = 128; off > 0; off >>= 1) {
        if (t < off) red[t] = fmaxf(red[t], red[t + off]);
        __syncthreads();
    }
    m = red[0];
    __syncthreads();

    float e0 = __expf(v0 - m), e1 = __expf(v1 - m);
    float e2 = __expf(v2 - m), e3 = __expf(v3 - m);
    red[t] = e0 + e1 + e2 + e3;
    __syncthreads();
    for (int off = 128; off > 0; off >>= 1) {
        if (t < off) red[t] += red[t + off];
        __syncthreads();
    }
    const float inv = 1.0f / red[0];

    const int we = ((i >> 7) + 1) << 7;      // wedge end (PV K bound)
    if (t < we)       row[t]       = f2b(t       <= i ? e0 * inv : 0.f);
    if (t + 256 < we) row[t + 256] = f2b(t + 256 <= i ? e1 * inv : 0.f);
    if (t + 512 < we) row[t + 512] = f2b(t + 512 <= i ? e2 * inv : 0.f);
    if (t + 768 < we) row[t + 768] = f2b(t + 768 <= i ? e3 * inv : 0.f);
}

// ---------------------------------------------------------------------------
// (B,H,L,D) fp32 -> (B,L,H*D) bf16
// ---------------------------------------------------------------------------
__global__ __launch_bounds__(256) void transpose_out_bf(
    const float* __restrict__ src, u16* __restrict__ dst)
{
    int idx = blockIdx.x * 256 + threadIdx.x;
    int d = idx & 63, h = (idx >> 6) & 15, l = (idx >> 10) & 1023, b = idx >> 20;
    dst[idx] = f2b(src[(((long long)(b * 16 + h)) * 1024 + l) * 64 + d]);
}

// ---------------------------------------------------------------------------
extern "C" void kernel_launch(void* const* d_in, const int* in_sizes, int n_in,
                              void* d_out, int out_size, void* d_ws, size_t ws_size,
                              hipStream_t stream)
{
    const float* x     = (const float*)d_in[0];
    const float* w_qkv = (const float*)d_in[1];
    const float* w_o   = (const float*)d_in[2];
    const float* log_p = (const float*)d_in[3];
    const float* log_a = (const float*)d_in[4];
    const float* w1    = (const float*)d_in[5];
    const float* b1    = (const float*)d_in[6];
    const float* w2    = (const float*)d_in[7];
    const float* b2    = (const float*)d_in[8];
    float* out = (float*)d_out;

    char* p = (char*)d_ws;
    float* qkv   = (float*)p;  p += 6291456ll * 4;   // (B,L,3,H,D) fp32
    u16* x_bf    = (u16*)p;    p += 2097152ll * 2;
    u16* wqkvT   = (u16*)p;    p += 3145728ll * 2;   // (3HD, HID)
    u16* woT     = (u16*)p;    p += 1048576ll * 2;   // (HID, HD)
    u16* q_bf    = (u16*)p;    p += 2097152ll * 2;   // (B,H,L,D)
    u16* k_bf    = (u16*)p;    p += 2097152ll * 2;
    u16* v_bf    = (u16*)p;    p += 2097152ll * 2;
    u16* vT      = (u16*)p;    p += 2097152ll * 2;   // (B,H,D,L)
    u16* scores  = (u16*)p;    p += 33554432ll * 2;  // (B,H,L,L) bf16, in-place
    float* attn  = (float*)p;  p += 2097152ll * 4;   // (B,H,L,D) fp32
    u16* attn_bf = (u16*)p;    p += 2097152ll * 2;   // (B,L,H*D)

    // casts / transposes of inputs
    cast_f2b<<<8192, 256, 0, stream>>>(x, x_bf, 2097152);
    transpose_cast_f2b<<<dim3(48, 16), 256, 0, stream>>>(w_qkv, wqkvT, HIDv, 3 * Hv * Dv);
    transpose_cast_f2b<<<dim3(16, 16), 256, 0, stream>>>(w_o, woT, Hv * Dv, HIDv);

    // 1. qkv = x @ w_qkv   (2048 x 3072 x 1024)
    gemm_bt<128, 128, 64, 64, false><<<dim3(24, 16, 1), 256, 0, stream>>>(
        x_bf, wqkvT, qkv, 2048, 3072, 1024, 0, 0, 0, 1.0f, 0, 0);

    // 2. rope + split -> bf16
    rope_split_bf<<<8192, 256, 0, stream>>>(qkv, q_bf, k_bf, v_bf);
    vtrans<<<dim3(16, 32), 256, 0, stream>>>(v_bf, vT);

    // 3. scores = (q @ k^T)/8, causal tiles only, bf16 out
    gemm_bt<128, 128, 64, 64, true><<<dim3(8, 8, 32), 256, 0, stream>>>(
        q_bf, k_bf, scores, 1024, 1024, 64,
        65536, 65536, 1048576, 0.125f, 1, 0);

    // 4. kerple + DAPE MLP (in-place, lower triangle)
    dape_mlp2<<<dim3(4, 1024, 2), 256, 0, stream>>>(
        scores, log_p, log_a, w1, b1, w2, b2);

    // 5. softmax rows (in-place, zero wedge for PV)
    softmax_bf<<<Bv * Hv * Lv, 256, 0, stream>>>(scores);

    // 6. attn = weights @ v  (triangular K)
    gemm_bt<128, 64, 64, 32, false><<<dim3(1, 8, 32), 256, 0, stream>>>(
        scores, vT, attn, 1024, 64, 1024,
        1048576, 65536, 65536, 1.0f, 0, 1);

    // 7. (B,H,L,D) -> (B,L,H*D) bf16
    transpose_out_bf<<<8192, 256, 0, stream>>>(attn, attn_bf);

    // 8. out = attn_fl @ w_o  (2048 x 1024 x 1024)
    gemm_bt<128, 128, 64, 64, false><<<dim3(8, 16, 1), 256, 0, stream>>>(
        attn_bf, woT, out, 2048, 1024, 1024, 0, 0, 0, 1.0f, 0, 0);
}

// Round 4
// 366.362 us; speedup vs baseline: 7.6022x; 1.3343x over previous
//
#include <hip/hip_runtime.h>
#include <math.h>

#define Bv 2
#define Lv 1024
#define Hv 16
#define Dv 64
#define HIDv 1024

typedef unsigned short u16;
typedef short bf16x8 __attribute__((ext_vector_type(8)));
typedef float f32x4 __attribute__((ext_vector_type(4)));

__device__ __forceinline__ u16 f2b(float f) {
    union { float f; unsigned u; } v; v.f = f;
    unsigned r = v.u + 0x7fffu + ((v.u >> 16) & 1u);
    return (u16)(r >> 16);
}
__device__ __forceinline__ float b2f(u16 h) {
    union { unsigned u; float f; } v; v.u = ((unsigned)h) << 16;
    return v.f;
}

// ---------------------------------------------------------------------------
// bf16 MFMA GEMM: C = alpha * A @ B^T
// A: MxK bf16 row-major; B: NxK bf16 row-major (i.e. B^T layout); C: MxN.
// 256 threads = 4 waves; block tile BM x BN; wave tile WM x WN.
// tri_skip: skip blocks with n0 > m0 (causal upper tiles).
// tri_k:    bound K-loop at m0+BM (causal PV).
// ---------------------------------------------------------------------------
template<int BM, int BN, int WM, int WN, bool CBF16>
__global__ __launch_bounds__(256) void gemm_bt(
    const u16* __restrict__ A, const u16* __restrict__ B, void* __restrict__ Cv,
    int M, int N, int K, long long sA, long long sB, long long sC,
    float alpha, int tri_skip, int tri_k)
{
    constexpr int NW = BN / WN;          // waves along N
    constexpr int MI = WM / 16;
    constexpr int NI = WN / 16;
    constexpr int LDT = 40;              // padded LDS row (bf16 elems): 80B stride
    __shared__ u16 As[BM * LDT];
    __shared__ u16 Bs[BN * LDT];

    const int m0 = blockIdx.y * BM;
    const int n0 = blockIdx.x * BN;
    if (tri_skip && n0 > m0) return;
    A += (long long)blockIdx.z * sA;
    B += (long long)blockIdx.z * sB;

    const int tid = threadIdx.x;
    const int lane = tid & 63;
    const int wave = tid >> 6;
    const int wm0 = (wave / NW) * WM;
    const int wn0 = (wave % NW) * WN;
    const int fr = lane & 15;            // fragment row (m or n)
    const int fq = lane >> 4;            // quad -> k chunk

    f32x4 acc[MI][NI];
    #pragma unroll
    for (int i = 0; i < MI; ++i)
        #pragma unroll
        for (int j = 0; j < NI; ++j) acc[i][j] = (f32x4){0.f, 0.f, 0.f, 0.f};

    int Kend = K;
    if (tri_k) { int kb = m0 + BM; if (kb < Kend) Kend = kb; }

    for (int k0 = 0; k0 < Kend; k0 += 32) {
        #pragma unroll
        for (int c = 0; c < (BM * 4) / 256; ++c) {
            int cid = tid + c * 256;
            int r = cid >> 2, ks = (cid & 3) * 8;
            *(bf16x8*)&As[r * LDT + ks] =
                *(const bf16x8*)(A + (long long)(m0 + r) * K + k0 + ks);
        }
        #pragma unroll
        for (int c = 0; c < (BN * 4) / 256; ++c) {
            int cid = tid + c * 256;
            int r = cid >> 2, ks = (cid & 3) * 8;
            *(bf16x8*)&Bs[r * LDT + ks] =
                *(const bf16x8*)(B + (long long)(n0 + r) * K + k0 + ks);
        }
        __syncthreads();
        bf16x8 af[MI], bfr[NI];
        #pragma unroll
        for (int i = 0; i < MI; ++i)
            af[i] = *(const bf16x8*)&As[(wm0 + i * 16 + fr) * LDT + fq * 8];
        #pragma unroll
        for (int j = 0; j < NI; ++j)
            bfr[j] = *(const bf16x8*)&Bs[(wn0 + j * 16 + fr) * LDT + fq * 8];
        #pragma unroll
        for (int i = 0; i < MI; ++i)
            #pragma unroll
            for (int j = 0; j < NI; ++j)
                acc[i][j] = __builtin_amdgcn_mfma_f32_16x16x32_bf16(
                    af[i], bfr[j], acc[i][j], 0, 0, 0);
        __syncthreads();
    }

    const long long cb = (long long)blockIdx.z * sC;
    #pragma unroll
    for (int i = 0; i < MI; ++i)
        #pragma unroll
        for (int j = 0; j < NI; ++j)
            #pragma unroll
            for (int r = 0; r < 4; ++r) {
                int row = m0 + wm0 + i * 16 + fq * 4 + r;
                int col = n0 + wn0 + j * 16 + fr;
                float v = acc[i][j][r] * alpha;
                if (CBF16) ((u16*)Cv)[cb + (long long)row * N + col] = f2b(v);
                else      ((float*)Cv)[cb + (long long)row * N + col] = v;
            }
}

// ---------------------------------------------------------------------------
// fp32 -> bf16 elementwise cast
// ---------------------------------------------------------------------------
__global__ __launch_bounds__(256) void cast_f2b(
    const float* __restrict__ src, u16* __restrict__ dst, int n)
{
    int i = blockIdx.x * 256 + threadIdx.x;
    if (i < n) dst[i] = f2b(src[i]);
}

// ---------------------------------------------------------------------------
// dst[n][m] = bf16(src[m][n]); grid (N/64, M/64), 256 threads
// ---------------------------------------------------------------------------
__global__ __launch_bounds__(256) void transpose_cast_f2b(
    const float* __restrict__ src, u16* __restrict__ dst, int M, int N)
{
    __shared__ float tile[64][65];
    const int m0 = blockIdx.y * 64, n0 = blockIdx.x * 64;
    const int tid = threadIdx.x;
    #pragma unroll
    for (int c = 0; c < 4; ++c) {
        int f = tid + c * 256;
        int r = f >> 4, cs = (f & 15) * 4;
        float4 v = *(const float4*)&src[(long long)(m0 + r) * N + n0 + cs];
        tile[r][cs] = v.x; tile[r][cs + 1] = v.y;
        tile[r][cs + 2] = v.z; tile[r][cs + 3] = v.w;
    }
    __syncthreads();
    int nl = tid >> 2, ms = (tid & 3) * 16;
    u16 outv[16];
    #pragma unroll
    for (int c = 0; c < 16; ++c) outv[c] = f2b(tile[ms + c][nl]);
    *(bf16x8*)&dst[(long long)(n0 + nl) * M + m0 + ms]     = *(bf16x8*)&outv[0];
    *(bf16x8*)&dst[(long long)(n0 + nl) * M + m0 + ms + 8] = *(bf16x8*)&outv[8];
}

// ---------------------------------------------------------------------------
// v (bh)[1024][64] bf16 -> vT (bh)[64][1024] bf16; grid (16, B*H)
// ---------------------------------------------------------------------------
__global__ __launch_bounds__(256) void vtrans(
    const u16* __restrict__ src, u16* __restrict__ dst)
{
    __shared__ u16 tile[64][65];
    const int bh = blockIdx.y;
    const int l0 = blockIdx.x * 64;
    const int tid = threadIdx.x;
    const u16* s = src + (long long)bh * 65536;
    u16* d = dst + (long long)bh * 65536;
    #pragma unroll
    for (int c = 0; c < 2; ++c) {
        int f = tid + c * 256;
        int r = f >> 3, cs = (f & 7) * 8;
        bf16x8 v = *(const bf16x8*)&s[(l0 + r) * 64 + cs];
        #pragma unroll
        for (int e = 0; e < 8; ++e) tile[r][cs + e] = (u16)v[e];
    }
    __syncthreads();
    int dl = tid >> 2, ls = (tid & 3) * 16;
    u16 outv[16];
    #pragma unroll
    for (int c = 0; c < 16; ++c) outv[c] = tile[ls + c][dl];
    *(bf16x8*)&d[dl * 1024 + l0 + ls]     = *(bf16x8*)&outv[0];
    *(bf16x8*)&d[dl * 1024 + l0 + ls + 8] = *(bf16x8*)&outv[8];
}

// ---------------------------------------------------------------------------
// RoPE + split qkv(B,L,3,H,D) fp32 -> q,k,v (B,H,L,D) bf16
// ---------------------------------------------------------------------------
__global__ __launch_bounds__(256) void rope_split_bf(
    const float* __restrict__ qkv,
    u16* __restrict__ q, u16* __restrict__ k, u16* __restrict__ v)
{
    int idx = blockIdx.x * 256 + threadIdx.x;
    int d = idx & 63;
    int l = (idx >> 6) & 1023;
    int h = (idx >> 16) & 15;
    int b = idx >> 20;
    const long long src = ((long long)(b * Lv + l) * 3) * 1024 + h * 64 + d;
    int i = d & 31;
    float inv_freq = __expf((float)i * -0.28782313662425574f); // -ln(10000)/32
    float arg = (float)l * inv_freq;
    float c, s;
    __sincosf(arg, &s, &c);
    float x0 = qkv[src];
    float xr0 = (d < 32) ? -qkv[src + 32] : qkv[src - 32];
    q[idx] = f2b(x0 * c + xr0 * s);
    float x1 = qkv[src + 1024];
    float xr1 = (d < 32) ? -qkv[src + 1024 + 32] : qkv[src + 1024 - 32];
    k[idx] = f2b(x1 * c + xr1 * s);
    v[idx] = f2b(qkv[src + 2048]);
}

// ---------------------------------------------------------------------------
// Kerple + DAPE MLP via MFMA, in-place on bf16 scores (B,H,L,L).
// Block = (jchunk of 256, i, b); 4 waves; each wave owns 16-position tiles.
// Layer1: comb(16x32) @ w1(32x32) = 2 MFMA; gelu; layer2 @ w2(32x16) = 1 MFMA.
// C->A layout transform between layers via per-wave LDS round-trip.
// ---------------------------------------------------------------------------
__global__ __launch_bounds__(256) void dape_mfma(
    u16* __restrict__ S,
    const float* __restrict__ log_p, const float* __restrict__ log_a,
    const float* __restrict__ w1, const float* __restrict__ b1,
    const float* __restrict__ w2, const float* __restrict__ b2)
{
    const int i = 1023 - blockIdx.y;         // longest rows first
    const int j0 = blockIdx.x * 256;
    if (j0 > i) return;
    const int b = blockIdx.z;

    __shared__ u16 comb[256 * 36];           // [j][ch], 36-ch pad (72B row)
    __shared__ u16 hid[4][16 * 36];          // per-wave hidden transpose buf
    __shared__ float sp[16], sa[16];

    const int tid = threadIdx.x;
    const int lane = tid & 63;
    const int wave = tid >> 6;
    const int fr = lane & 15;
    const int fq = lane >> 4;

    if (tid < 16) {
        sp[tid] = log1pf(__expf(log_p[tid]));  // softplus
        sa[tid] = log1pf(__expf(log_a[tid]));
    }

    // weight fragments (registers, once per block); B[n=lane&15][k=fq*8+e]
    bf16x8 B1a, B1b, B2f;
    #pragma unroll
    for (int e = 0; e < 8; ++e) {
        int c = fq * 8 + e;
        B1a[e] = (short)f2b(w1[c * 32 + fr]);        // n = o in [0,16)
        B1b[e] = (short)f2b(w1[c * 32 + 16 + fr]);   // n = o in [16,32)
        B2f[e] = (short)f2b(w2[c * 16 + fr]);        // n = h, k = o
    }
    const float b1a = b1[fr], b1b = b1[16 + fr], b2v = b2[fr];

    __syncthreads();

    // stage comb[j][0..31]: 16 score channels (head-strided loads, like the
    // round-3 kernel: 128B runs per head per wave) + 16 kerple channels.
    {
        const int j = j0 + tid;
        const long long base = (long long)b * 16 * 1048576 + (long long)i * 1024 + j;
        u16 row[32];
        #pragma unroll
        for (int h = 0; h < 16; ++h)
            row[h] = S[base + (long long)h * 1048576];
        const float dist = (float)(i - j > 0 ? i - j : 0);
        #pragma unroll
        for (int h = 0; h < 16; ++h)
            row[16 + h] = f2b(-sp[h] * log1pf(sa[h] * dist));
        #pragma unroll
        for (int c = 0; c < 4; ++c)
            *(bf16x8*)&comb[tid * 36 + c * 8] = *(bf16x8*)&row[c * 8];
    }
    __syncthreads();

    // tiles of 16 positions; wave w owns tiles w, w+4, ...
    for (int t = wave; t < 16; t += 4) {
        const int jt = j0 + t * 16;
        if (jt > i) continue;                // whole tile above diagonal

        bf16x8 A1 = *(const bf16x8*)&comb[(t * 16 + fr) * 36 + fq * 8];
        f32x4 z = (f32x4){0.f, 0.f, 0.f, 0.f};
        f32x4 ac1a = __builtin_amdgcn_mfma_f32_16x16x32_bf16(A1, B1a, z, 0, 0, 0);
        f32x4 ac1b = __builtin_amdgcn_mfma_f32_16x16x32_bf16(A1, B1b, z, 0, 0, 0);

        // gelu + write hidden (bf16) to per-wave transpose buffer
        #pragma unroll
        for (int r = 0; r < 4; ++r) {
            float v0 = ac1a[r] + b1a;
            float v1 = ac1b[r] + b1b;
            float g0 = 0.5f * v0 * (1.f + erff(v0 * 0.70710678118654752f));
            float g1 = 0.5f * v1 * (1.f + erff(v1 * 0.70710678118654752f));
            hid[wave][(fq * 4 + r) * 36 + fr]      = f2b(g0);
            hid[wave][(fq * 4 + r) * 36 + 16 + fr] = f2b(g1);
        }
        // same-wave write->read: compiler inserts lgkmcnt wait, no barrier
        bf16x8 A2 = *(const bf16x8*)&hid[wave][fr * 36 + fq * 8];
        f32x4 ac2 = __builtin_amdgcn_mfma_f32_16x16x32_bf16(A2, B2f, z, 0, 0, 0);

        // final: scores + kerple + refined; lane holds h=fr, rows jt+fq*4+r
        const long long ob = (long long)b * 16 * 1048576 +
                             (long long)fr * 1048576 + (long long)i * 1024;
        #pragma unroll
        for (int r = 0; r < 4; ++r) {
            int j = jt + fq * 4 + r;
            if (j <= i) {
                int jl = t * 16 + fq * 4 + r;
                float scv = b2f(comb[jl * 36 + fr]);
                float kv  = b2f(comb[jl * 36 + 16 + fr]);
                S[ob + j] = f2b(scv + kv + ac2[r] + b2v);
            }
        }
    }
}

// ---------------------------------------------------------------------------
// Row softmax on bf16 logits, in-place -> bf16 weights.
// One block per (b,h,i) row; masks j>i; zero-fills the wedge up to the next
// 128 boundary (the triangular PV GEMM reads K up to m0+128).
// ---------------------------------------------------------------------------
__global__ __launch_bounds__(256) void softmax_bf(u16* __restrict__ S)
{
    const long long r = blockIdx.x;          // (b*16 + h)*1024 + i
    const int i = (int)(r & 1023);
    u16* row = S + r * 1024;
    const int t = threadIdx.x;
    __shared__ float red[256];

    float v0 = (t       <= i) ? b2f(row[t])       : -3.0e38f;
    float v1 = (t + 256 <= i) ? b2f(row[t + 256]) : -3.0e38f;
    float v2 = (t + 512 <= i) ? b2f(row[t + 512]) : -3.0e38f;
    float v3 = (t + 768 <= i) ? b2f(row[t + 768]) : -3.0e38f;
    float m = fmaxf(fmaxf(v0, v1), fmaxf(v2, v3));
    red[t] = m;
    __syncthreads();
    for (int off = 128; off > 0; off >>= 1) {
        if (t < off) red[t] = fmaxf(red[t], red[t + off]);
        __syncthreads();
    }
    m = red[0];
    __syncthreads();

    float e0 = __expf(v0 - m), e1 = __expf(v1 - m);
    float e2 = __expf(v2 - m), e3 = __expf(v3 - m);
    red[t] = e0 + e1 + e2 + e3;
    __syncthreads();
    for (int off = 128; off > 0; off >>= 1) {
        if (t < off) red[t] += red[t + off];
        __syncthreads();
    }
    const float inv = 1.0f / red[0];

    const int we = ((i >> 7) + 1) << 7;      // wedge end (PV K bound)
    if (t < we)       row[t]       = f2b(t       <= i ? e0 * inv : 0.f);
    if (t + 256 < we) row[t + 256] = f2b(t + 256 <= i ? e1 * inv : 0.f);
    if (t + 512 < we) row[t + 512] = f2b(t + 512 <= i ? e2 * inv : 0.f);
    if (t + 768 < we) row[t + 768] = f2b(t + 768 <= i ? e3 * inv : 0.f);
}

// ---------------------------------------------------------------------------
// (B,H,L,D) fp32 -> (B,L,H*D) bf16
// ---------------------------------------------------------------------------
__global__ __launch_bounds__(256) void transpose_out_bf(
    const float* __restrict__ src, u16* __restrict__ dst)
{
    int idx = blockIdx.x * 256 + threadIdx.x;
    int d = idx & 63, h = (idx >> 6) & 15, l = (idx >> 10) & 1023, b = idx >> 20;
    dst[idx] = f2b(src[(((long long)(b * 16 + h)) * 1024 + l) * 64 + d]);
}

// ---------------------------------------------------------------------------
extern "C" void kernel_launch(void* const* d_in, const int* in_sizes, int n_in,
                              void* d_out, int out_size, void* d_ws, size_t ws_size,
                              hipStream_t stream)
{
    const float* x     = (const float*)d_in[0];
    const float* w_qkv = (const float*)d_in[1];
    const float* w_o   = (const float*)d_in[2];
    const float* log_p = (const float*)d_in[3];
    const float* log_a = (const float*)d_in[4];
    const float* w1    = (const float*)d_in[5];
    const float* b1    = (const float*)d_in[6];
    const float* w2    = (const float*)d_in[7];
    const float* b2    = (const float*)d_in[8];
    float* out = (float*)d_out;

    char* p = (char*)d_ws;
    float* qkv   = (float*)p;  p += 6291456ll * 4;   // (B,L,3,H,D) fp32
    u16* x_bf    = (u16*)p;    p += 2097152ll * 2;
    u16* wqkvT   = (u16*)p;    p += 3145728ll * 2;   // (3HD, HID)
    u16* woT     = (u16*)p;    p += 1048576ll * 2;   // (HID, HD)
    u16* q_bf    = (u16*)p;    p += 2097152ll * 2;   // (B,H,L,D)
    u16* k_bf    = (u16*)p;    p += 2097152ll * 2;
    u16* v_bf    = (u16*)p;    p += 2097152ll * 2;
    u16* vT      = (u16*)p;    p += 2097152ll * 2;   // (B,H,D,L)
    u16* scores  = (u16*)p;    p += 33554432ll * 2;  // (B,H,L,L) bf16, in-place
    float* attn  = (float*)p;  p += 2097152ll * 4;   // (B,H,L,D) fp32
    u16* attn_bf = (u16*)p;    p += 2097152ll * 2;   // (B,L,H*D)

    // casts / transposes of inputs
    cast_f2b<<<8192, 256, 0, stream>>>(x, x_bf, 2097152);
    transpose_cast_f2b<<<dim3(48, 16), 256, 0, stream>>>(w_qkv, wqkvT, HIDv, 3 * Hv * Dv);
    transpose_cast_f2b<<<dim3(16, 16), 256, 0, stream>>>(w_o, woT, Hv * Dv, HIDv);

    // 1. qkv = x @ w_qkv   (2048 x 3072 x 1024)
    gemm_bt<128, 128, 64, 64, false><<<dim3(24, 16, 1), 256, 0, stream>>>(
        x_bf, wqkvT, qkv, 2048, 3072, 1024, 0, 0, 0, 1.0f, 0, 0);

    // 2. rope + split -> bf16
    rope_split_bf<<<8192, 256, 0, stream>>>(qkv, q_bf, k_bf, v_bf);
    vtrans<<<dim3(16, 32), 256, 0, stream>>>(v_bf, vT);

    // 3. scores = (q @ k^T)/8, causal tiles only, bf16 out
    gemm_bt<128, 128, 64, 64, true><<<dim3(8, 8, 32), 256, 0, stream>>>(
        q_bf, k_bf, scores, 1024, 1024, 64,
        65536, 65536, 1048576, 0.125f, 1, 0);

    // 4. kerple + DAPE MLP via MFMA (in-place, lower triangle)
    dape_mfma<<<dim3(4, 1024, 2), 256, 0, stream>>>(
        scores, log_p, log_a, w1, b1, w2, b2);

    // 5. softmax rows (in-place, zero wedge for PV)
    softmax_bf<<<Bv * Hv * Lv, 256, 0, stream>>>(scores);

    // 6. attn = weights @ v  (triangular K)
    gemm_bt<128, 64, 64, 32, false><<<dim3(1, 8, 32), 256, 0, stream>>>(
        scores, vT, attn, 1024, 64, 1024,
        1048576, 65536, 65536, 1.0f, 0, 1);

    // 7. (B,H,L,D) -> (B,L,H*D) bf16
    transpose_out_bf<<<8192, 256, 0, stream>>>(attn, attn_bf);

    // 8. out = attn_fl @ w_o  (2048 x 1024 x 1024)
    gemm_bt<128, 128, 64, 64, false><<<dim3(8, 16, 1), 256, 0, stream>>>(
        attn_bf, woT, out, 2048, 1024, 1024, 0, 0, 0, 1.0f, 0, 0);
}

// Round 5
// 333.835 us; speedup vs baseline: 8.3430x; 1.0974x over previous
//
#include <hip/hip_runtime.h>
#include <math.h>

#define Bv 2
#define Lv 1024
#define Hv 16
#define Dv 64
#define HIDv 1024

typedef unsigned short u16;
typedef short bf16x8 __attribute__((ext_vector_type(8)));
typedef float f32x4 __attribute__((ext_vector_type(4)));

__device__ __forceinline__ u16 f2b(float f) {
    union { float f; unsigned u; } v; v.f = f;
    unsigned r = v.u + 0x7fffu + ((v.u >> 16) & 1u);
    return (u16)(r >> 16);
}
__device__ __forceinline__ float b2f(u16 h) {
    union { unsigned u; float f; } v; v.u = ((unsigned)h) << 16;
    return v.f;
}

// gelu with A&S 7.1.26 erf (max abs err 1.5e-7): ~15 VALU inst vs libm ~60.
__device__ __forceinline__ float gelu_fast(float x) {
    float y = x * 0.70710678118654752f;
    float a = fabsf(y);
    float t = 1.0f / (1.0f + 0.3275911f * a);
    float p = t * (0.254829592f + t * (-0.284496736f +
              t * (1.421413741f + t * (-1.453152027f + t * 1.061405429f))));
    float e = __expf(-a * a);
    float erfv = copysignf(1.0f - p * e, y);
    return 0.5f * x * (1.0f + erfv);
}

// ---------------------------------------------------------------------------
// bf16 MFMA GEMM: C = alpha * A @ B^T
// A: MxK bf16 row-major; B: NxK bf16 row-major (i.e. B^T layout); C: MxN.
// 256 threads = 4 waves; block tile BM x BN; wave tile WM x WN.
// tri_skip: skip blocks with n0 > m0 (causal upper tiles).
// tri_k:    bound K-loop at m0+BM (causal PV).
// aout:     write bf16 into (B,L,H*D) attention layout, z = b*16+h.
// ---------------------------------------------------------------------------
template<int BM, int BN, int WM, int WN, bool CBF16>
__global__ __launch_bounds__(256) void gemm_bt(
    const u16* __restrict__ A, const u16* __restrict__ B, void* __restrict__ Cv,
    int M, int N, int K, long long sA, long long sB, long long sC,
    float alpha, int tri_skip, int tri_k, int aout)
{
    constexpr int NW = BN / WN;          // waves along N
    constexpr int MI = WM / 16;
    constexpr int NI = WN / 16;
    constexpr int LDT = 40;              // padded LDS row (bf16 elems): 80B stride
    __shared__ u16 As[BM * LDT];
    __shared__ u16 Bs[BN * LDT];

    const int m0 = blockIdx.y * BM;
    const int n0 = blockIdx.x * BN;
    if (tri_skip && n0 > m0) return;
    A += (long long)blockIdx.z * sA;
    B += (long long)blockIdx.z * sB;

    const int tid = threadIdx.x;
    const int lane = tid & 63;
    const int wave = tid >> 6;
    const int wm0 = (wave / NW) * WM;
    const int wn0 = (wave % NW) * WN;
    const int fr = lane & 15;            // fragment row (m or n)
    const int fq = lane >> 4;            // quad -> k chunk

    f32x4 acc[MI][NI];
    #pragma unroll
    for (int i = 0; i < MI; ++i)
        #pragma unroll
        for (int j = 0; j < NI; ++j) acc[i][j] = (f32x4){0.f, 0.f, 0.f, 0.f};

    int Kend = K;
    if (tri_k) { int kb = m0 + BM; if (kb < Kend) Kend = kb; }

    for (int k0 = 0; k0 < Kend; k0 += 32) {
        #pragma unroll
        for (int c = 0; c < (BM * 4) / 256; ++c) {
            int cid = tid + c * 256;
            int r = cid >> 2, ks = (cid & 3) * 8;
            *(bf16x8*)&As[r * LDT + ks] =
                *(const bf16x8*)(A + (long long)(m0 + r) * K + k0 + ks);
        }
        #pragma unroll
        for (int c = 0; c < (BN * 4) / 256; ++c) {
            int cid = tid + c * 256;
            int r = cid >> 2, ks = (cid & 3) * 8;
            *(bf16x8*)&Bs[r * LDT + ks] =
                *(const bf16x8*)(B + (long long)(n0 + r) * K + k0 + ks);
        }
        __syncthreads();
        bf16x8 af[MI], bfr[NI];
        #pragma unroll
        for (int i = 0; i < MI; ++i)
            af[i] = *(const bf16x8*)&As[(wm0 + i * 16 + fr) * LDT + fq * 8];
        #pragma unroll
        for (int j = 0; j < NI; ++j)
            bfr[j] = *(const bf16x8*)&Bs[(wn0 + j * 16 + fr) * LDT + fq * 8];
        #pragma unroll
        for (int i = 0; i < MI; ++i)
            #pragma unroll
            for (int j = 0; j < NI; ++j)
                acc[i][j] = __builtin_amdgcn_mfma_f32_16x16x32_bf16(
                    af[i], bfr[j], acc[i][j], 0, 0, 0);
        __syncthreads();
    }

    long long cb;
    long long ldc = N;
    if (aout) {   // (B,L,H*D) bf16: z = b*16+h
        cb = (long long)(blockIdx.z >> 4) * 1048576 + (blockIdx.z & 15) * 64;
        ldc = 1024;
    } else {
        cb = (long long)blockIdx.z * sC;
    }
    #pragma unroll
    for (int i = 0; i < MI; ++i)
        #pragma unroll
        for (int j = 0; j < NI; ++j)
            #pragma unroll
            for (int r = 0; r < 4; ++r) {
                int row = m0 + wm0 + i * 16 + fq * 4 + r;
                int col = n0 + wn0 + j * 16 + fr;
                float v = acc[i][j][r] * alpha;
                if (CBF16 || aout)
                    ((u16*)Cv)[cb + (long long)row * ldc + col] = f2b(v);
                else
                    ((float*)Cv)[cb + (long long)row * ldc + col] = v;
            }
}

// ---------------------------------------------------------------------------
// fp32 -> bf16 elementwise cast
// ---------------------------------------------------------------------------
__global__ __launch_bounds__(256) void cast_f2b(
    const float* __restrict__ src, u16* __restrict__ dst, int n)
{
    int i = blockIdx.x * 256 + threadIdx.x;
    if (i < n) dst[i] = f2b(src[i]);
}

// ---------------------------------------------------------------------------
// Kerple table: ktab[dist][h] = bf16(-softplus(log_p[h]) * log1p(softplus(log_a[h])*dist))
// grid 64 x 256
// ---------------------------------------------------------------------------
__global__ __launch_bounds__(256) void kerple_tab(
    const float* __restrict__ log_p, const float* __restrict__ log_a,
    u16* __restrict__ ktab)
{
    int idx = blockIdx.x * 256 + threadIdx.x;   // 16384
    int h = idx & 15, dist = idx >> 4;
    float p = log1pf(__expf(log_p[h]));
    float a = log1pf(__expf(log_a[h]));
    ktab[idx] = f2b(-p * log1pf(a * (float)dist));
}

// ---------------------------------------------------------------------------
// dst[n][m] = bf16(src[m][n]); grid (N/64, M/64), 256 threads
// ---------------------------------------------------------------------------
__global__ __launch_bounds__(256) void transpose_cast_f2b(
    const float* __restrict__ src, u16* __restrict__ dst, int M, int N)
{
    __shared__ float tile[64][65];
    const int m0 = blockIdx.y * 64, n0 = blockIdx.x * 64;
    const int tid = threadIdx.x;
    #pragma unroll
    for (int c = 0; c < 4; ++c) {
        int f = tid + c * 256;
        int r = f >> 4, cs = (f & 15) * 4;
        float4 v = *(const float4*)&src[(long long)(m0 + r) * N + n0 + cs];
        tile[r][cs] = v.x; tile[r][cs + 1] = v.y;
        tile[r][cs + 2] = v.z; tile[r][cs + 3] = v.w;
    }
    __syncthreads();
    int nl = tid >> 2, ms = (tid & 3) * 16;
    u16 outv[16];
    #pragma unroll
    for (int c = 0; c < 16; ++c) outv[c] = f2b(tile[ms + c][nl]);
    *(bf16x8*)&dst[(long long)(n0 + nl) * M + m0 + ms]     = *(bf16x8*)&outv[0];
    *(bf16x8*)&dst[(long long)(n0 + nl) * M + m0 + ms + 8] = *(bf16x8*)&outv[8];
}

// ---------------------------------------------------------------------------
// v (bh)[1024][64] bf16 -> vT (bh)[64][1024] bf16; grid (16, B*H)
// ---------------------------------------------------------------------------
__global__ __launch_bounds__(256) void vtrans(
    const u16* __restrict__ src, u16* __restrict__ dst)
{
    __shared__ u16 tile[64][65];
    const int bh = blockIdx.y;
    const int l0 = blockIdx.x * 64;
    const int tid = threadIdx.x;
    const u16* s = src + (long long)bh * 65536;
    u16* d = dst + (long long)bh * 65536;
    #pragma unroll
    for (int c = 0; c < 2; ++c) {
        int f = tid + c * 256;
        int r = f >> 3, cs = (f & 7) * 8;
        bf16x8 v = *(const bf16x8*)&s[(l0 + r) * 64 + cs];
        #pragma unroll
        for (int e = 0; e < 8; ++e) tile[r][cs + e] = (u16)v[e];
    }
    __syncthreads();
    int dl = tid >> 2, ls = (tid & 3) * 16;
    u16 outv[16];
    #pragma unroll
    for (int c = 0; c < 16; ++c) outv[c] = tile[ls + c][dl];
    *(bf16x8*)&d[dl * 1024 + l0 + ls]     = *(bf16x8*)&outv[0];
    *(bf16x8*)&d[dl * 1024 + l0 + ls + 8] = *(bf16x8*)&outv[8];
}

// ---------------------------------------------------------------------------
// RoPE + split qkv(B,L,3,H,D) fp32 -> q,k,v (B,H,L,D) bf16
// ---------------------------------------------------------------------------
__global__ __launch_bounds__(256) void rope_split_bf(
    const float* __restrict__ qkv,
    u16* __restrict__ q, u16* __restrict__ k, u16* __restrict__ v)
{
    int idx = blockIdx.x * 256 + threadIdx.x;
    int d = idx & 63;
    int l = (idx >> 6) & 1023;
    int h = (idx >> 16) & 15;
    int b = idx >> 20;
    const long long src = ((long long)(b * Lv + l) * 3) * 1024 + h * 64 + d;
    int i = d & 31;
    float inv_freq = __expf((float)i * -0.28782313662425574f); // -ln(10000)/32
    float arg = (float)l * inv_freq;
    float c, s;
    __sincosf(arg, &s, &c);
    float x0 = qkv[src];
    float xr0 = (d < 32) ? -qkv[src + 32] : qkv[src - 32];
    q[idx] = f2b(x0 * c + xr0 * s);
    float x1 = qkv[src + 1024];
    float xr1 = (d < 32) ? -qkv[src + 1024 + 32] : qkv[src + 1024 - 32];
    k[idx] = f2b(x1 * c + xr1 * s);
    v[idx] = f2b(qkv[src + 2048]);
}

// ---------------------------------------------------------------------------
// Kerple + DAPE MLP via MFMA, in-place on bf16 scores (B,H,L,L).
// Block = (jchunk of 256, i, b); 4 waves; each wave owns 16-position tiles.
// Layer1: comb(16x32) @ w1(32x32) = 2 MFMA; gelu; layer2 @ w2(32x16) = 1 MFMA.
// Kerple channels come from the precomputed ktab (2 vector loads, no log1pf).
// ---------------------------------------------------------------------------
__global__ __launch_bounds__(256) void dape_mfma(
    u16* __restrict__ S, const u16* __restrict__ ktab,
    const float* __restrict__ w1, const float* __restrict__ b1,
    const float* __restrict__ w2, const float* __restrict__ b2)
{
    const int i = 1023 - blockIdx.y;         // longest rows first
    const int j0 = blockIdx.x * 256;
    if (j0 > i) return;
    const int b = blockIdx.z;

    __shared__ u16 comb[256 * 36];           // [j][ch], 36-ch pad (72B row)
    __shared__ u16 hid[4][16 * 36];          // per-wave hidden transpose buf

    const int tid = threadIdx.x;
    const int lane = tid & 63;
    const int wave = tid >> 6;
    const int fr = lane & 15;
    const int fq = lane >> 4;

    // weight fragments (registers, once per block); B[n=lane&15][k=fq*8+e]
    bf16x8 B1a, B1b, B2f;
    #pragma unroll
    for (int e = 0; e < 8; ++e) {
        int c = fq * 8 + e;
        B1a[e] = (short)f2b(w1[c * 32 + fr]);        // n = o in [0,16)
        B1b[e] = (short)f2b(w1[c * 32 + 16 + fr]);   // n = o in [16,32)
        B2f[e] = (short)f2b(w2[c * 16 + fr]);        // n = h, k = o
    }
    const float b1a = b1[fr], b1b = b1[16 + fr], b2v = b2[fr];

    // stage comb[j][0..31]: 16 score channels (head-strided, coalesced per
    // head) + 16 kerple channels from ktab (two 16B vector loads).
    {
        const int j = j0 + tid;
        const long long base = (long long)b * 16 * 1048576 + (long long)i * 1024 + j;
        u16 row[32];
        #pragma unroll
        for (int h = 0; h < 16; ++h)
            row[h] = S[base + (long long)h * 1048576];
        const int dist = (i - j > 0) ? (i - j) : 0;
        *(bf16x8*)&row[16] = *(const bf16x8*)&ktab[dist * 16];
        *(bf16x8*)&row[24] = *(const bf16x8*)&ktab[dist * 16 + 8];
        #pragma unroll
        for (int c = 0; c < 4; ++c)
            *(bf16x8*)&comb[tid * 36 + c * 8] = *(bf16x8*)&row[c * 8];
    }
    __syncthreads();

    // tiles of 16 positions; wave w owns tiles w, w+4, ...
    for (int t = wave; t < 16; t += 4) {
        const int jt = j0 + t * 16;
        if (jt > i) continue;                // whole tile above diagonal

        bf16x8 A1 = *(const bf16x8*)&comb[(t * 16 + fr) * 36 + fq * 8];
        f32x4 z = (f32x4){0.f, 0.f, 0.f, 0.f};
        f32x4 ac1a = __builtin_amdgcn_mfma_f32_16x16x32_bf16(A1, B1a, z, 0, 0, 0);
        f32x4 ac1b = __builtin_amdgcn_mfma_f32_16x16x32_bf16(A1, B1b, z, 0, 0, 0);

        // gelu + write hidden (bf16) to per-wave transpose buffer
        #pragma unroll
        for (int r = 0; r < 4; ++r) {
            float g0 = gelu_fast(ac1a[r] + b1a);
            float g1 = gelu_fast(ac1b[r] + b1b);
            hid[wave][(fq * 4 + r) * 36 + fr]      = f2b(g0);
            hid[wave][(fq * 4 + r) * 36 + 16 + fr] = f2b(g1);
        }
        // same-wave write->read: compiler inserts lgkmcnt wait, no barrier
        bf16x8 A2 = *(const bf16x8*)&hid[wave][fr * 36 + fq * 8];
        f32x4 ac2 = __builtin_amdgcn_mfma_f32_16x16x32_bf16(A2, B2f, z, 0, 0, 0);

        // final: scores + kerple + refined; lane holds h=fr, rows jt+fq*4+r
        const long long ob = (long long)b * 16 * 1048576 +
                             (long long)fr * 1048576 + (long long)i * 1024;
        #pragma unroll
        for (int r = 0; r < 4; ++r) {
            int j = jt + fq * 4 + r;
            if (j <= i) {
                int jl = t * 16 + fq * 4 + r;
                float scv = b2f(comb[jl * 36 + fr]);
                float kv  = b2f(comb[jl * 36 + 16 + fr]);
                S[ob + j] = f2b(scv + kv + ac2[r] + b2v);
            }
        }
    }
}

// ---------------------------------------------------------------------------
// Row softmax on bf16 logits, in-place -> bf16 weights.
// One block per (b,h,i) row; masks j>i; zero-fills the wedge up to the next
// 128 boundary (the triangular PV GEMM reads K up to m0+128).
// ---------------------------------------------------------------------------
__global__ __launch_bounds__(256) void softmax_bf(u16* __restrict__ S)
{
    const long long r = blockIdx.x;          // (b*16 + h)*1024 + i
    const int i = (int)(r & 1023);
    u16* row = S + r * 1024;
    const int t = threadIdx.x;
    __shared__ float red[256];

    float v0 = (t       <= i) ? b2f(row[t])       : -3.0e38f;
    float v1 = (t + 256 <= i) ? b2f(row[t + 256]) : -3.0e38f;
    float v2 = (t + 512 <= i) ? b2f(row[t + 512]) : -3.0e38f;
    float v3 = (t + 768 <= i) ? b2f(row[t + 768]) : -3.0e38f;
    float m = fmaxf(fmaxf(v0, v1), fmaxf(v2, v3));
    red[t] = m;
    __syncthreads();
    for (int off = 128; off > 0; off >>= 1) {
        if (t < off) red[t] = fmaxf(red[t], red[t + off]);
        __syncthreads();
    }
    m = red[0];
    __syncthreads();

    float e0 = __expf(v0 - m), e1 = __expf(v1 - m);
    float e2 = __expf(v2 - m), e3 = __expf(v3 - m);
    red[t] = e0 + e1 + e2 + e3;
    __syncthreads();
    for (int off = 128; off > 0; off >>= 1) {
        if (t < off) red[t] += red[t + off];
        __syncthreads();
    }
    const float inv = 1.0f / red[0];

    const int we = ((i >> 7) + 1) << 7;      // wedge end (PV K bound)
    if (t < we)       row[t]       = f2b(t       <= i ? e0 * inv : 0.f);
    if (t + 256 < we) row[t + 256] = f2b(t + 256 <= i ? e1 * inv : 0.f);
    if (t + 512 < we) row[t + 512] = f2b(t + 512 <= i ? e2 * inv : 0.f);
    if (t + 768 < we) row[t + 768] = f2b(t + 768 <= i ? e3 * inv : 0.f);
}

// ---------------------------------------------------------------------------
extern "C" void kernel_launch(void* const* d_in, const int* in_sizes, int n_in,
                              void* d_out, int out_size, void* d_ws, size_t ws_size,
                              hipStream_t stream)
{
    const float* x     = (const float*)d_in[0];
    const float* w_qkv = (const float*)d_in[1];
    const float* w_o   = (const float*)d_in[2];
    const float* log_p = (const float*)d_in[3];
    const float* log_a = (const float*)d_in[4];
    const float* w1    = (const float*)d_in[5];
    const float* b1    = (const float*)d_in[6];
    const float* w2    = (const float*)d_in[7];
    const float* b2    = (const float*)d_in[8];
    float* out = (float*)d_out;

    char* p = (char*)d_ws;
    float* qkv   = (float*)p;  p += 6291456ll * 4;   // (B,L,3,H,D) fp32
    u16* x_bf    = (u16*)p;    p += 2097152ll * 2;
    u16* wqkvT   = (u16*)p;    p += 3145728ll * 2;   // (3HD, HID)
    u16* woT     = (u16*)p;    p += 1048576ll * 2;   // (HID, HD)
    u16* q_bf    = (u16*)p;    p += 2097152ll * 2;   // (B,H,L,D)
    u16* k_bf    = (u16*)p;    p += 2097152ll * 2;
    u16* v_bf    = (u16*)p;    p += 2097152ll * 2;
    u16* vT      = (u16*)p;    p += 2097152ll * 2;   // (B,H,D,L)
    u16* scores  = (u16*)p;    p += 33554432ll * 2;  // (B,H,L,L) bf16, in-place
    u16* attn_bf = (u16*)p;    p += 2097152ll * 2;   // (B,L,H*D)
    u16* ktab    = (u16*)p;    p += 16384ll * 2;     // kerple[dist][h]

    // casts / transposes / tables
    cast_f2b<<<8192, 256, 0, stream>>>(x, x_bf, 2097152);
    transpose_cast_f2b<<<dim3(48, 16), 256, 0, stream>>>(w_qkv, wqkvT, HIDv, 3 * Hv * Dv);
    transpose_cast_f2b<<<dim3(16, 16), 256, 0, stream>>>(w_o, woT, Hv * Dv, HIDv);
    kerple_tab<<<64, 256, 0, stream>>>(log_p, log_a, ktab);

    // 1. qkv = x @ w_qkv   (2048 x 3072 x 1024)
    gemm_bt<128, 128, 64, 64, false><<<dim3(24, 16, 1), 256, 0, stream>>>(
        x_bf, wqkvT, qkv, 2048, 3072, 1024, 0, 0, 0, 1.0f, 0, 0, 0);

    // 2. rope + split -> bf16
    rope_split_bf<<<8192, 256, 0, stream>>>(qkv, q_bf, k_bf, v_bf);
    vtrans<<<dim3(16, 32), 256, 0, stream>>>(v_bf, vT);

    // 3. scores = (q @ k^T)/8, causal tiles only, bf16 out
    gemm_bt<128, 128, 64, 64, true><<<dim3(8, 8, 32), 256, 0, stream>>>(
        q_bf, k_bf, scores, 1024, 1024, 64,
        65536, 65536, 1048576, 0.125f, 1, 0, 0);

    // 4. kerple + DAPE MLP via MFMA (in-place, lower triangle)
    dape_mfma<<<dim3(4, 1024, 2), 256, 0, stream>>>(
        scores, ktab, w1, b1, w2, b2);

    // 5. softmax rows (in-place, zero wedge for PV)
    softmax_bf<<<Bv * Hv * Lv, 256, 0, stream>>>(scores);

    // 6. attn_bf = weights @ v, written directly to (B,L,H*D) bf16
    gemm_bt<128, 64, 64, 32, false><<<dim3(1, 8, 32), 256, 0, stream>>>(
        scores, vT, attn_bf, 1024, 64, 1024,
        1048576, 65536, 0, 1.0f, 0, 1, 1);

    // 7. out = attn_fl @ w_o  (2048 x 1024 x 1024)
    gemm_bt<128, 128, 64, 64, false><<<dim3(8, 16, 1), 256, 0, stream>>>(
        attn_bf, woT, out, 2048, 1024, 1024, 0, 0, 0, 1.0f, 0, 0, 0);
}

// Round 6
// 278.190 us; speedup vs baseline: 10.0118x; 1.2000x over previous
//
#include <hip/hip_runtime.h>
#include <math.h>

#define Bv 2
#define Lv 1024
#define Hv 16
#define Dv 64
#define HIDv 1024

typedef unsigned short u16;
typedef short bf16x8 __attribute__((ext_vector_type(8)));
typedef unsigned short u16x4 __attribute__((ext_vector_type(4)));
typedef float f32x4 __attribute__((ext_vector_type(4)));

__device__ __forceinline__ u16 f2b(float f) {
    union { float f; unsigned u; } v; v.f = f;
    unsigned r = v.u + 0x7fffu + ((v.u >> 16) & 1u);
    return (u16)(r >> 16);
}
__device__ __forceinline__ float b2f(u16 h) {
    union { unsigned u; float f; } v; v.u = ((unsigned)h) << 16;
    return v.f;
}

// gelu with A&S 7.1.26 erf (max abs err 1.5e-7): ~15 VALU inst vs libm ~60.
__device__ __forceinline__ float gelu_fast(float x) {
    float y = x * 0.70710678118654752f;
    float a = fabsf(y);
    float t = 1.0f / (1.0f + 0.3275911f * a);
    float p = t * (0.254829592f + t * (-0.284496736f +
              t * (1.421413741f + t * (-1.453152027f + t * 1.061405429f))));
    float e = __expf(-a * a);
    float erfv = copysignf(1.0f - p * e, y);
    return 0.5f * x * (1.0f + erfv);
}

// ---------------------------------------------------------------------------
// bf16 MFMA GEMM: C = alpha * A @ B^T
// A: MxK bf16 row-major; B: NxK bf16 row-major (i.e. B^T layout); C: MxN.
// tri_skip: skip blocks with n0 > m0. tri_k: bound K at m0+BM (causal PV).
// aout: write bf16 into (B,L,H*D) attention layout, z = b*16+h.
// ---------------------------------------------------------------------------
template<int BM, int BN, int WM, int WN, bool CBF16>
__global__ __launch_bounds__(256) void gemm_bt(
    const u16* __restrict__ A, const u16* __restrict__ B, void* __restrict__ Cv,
    int M, int N, int K, long long sA, long long sB, long long sC,
    float alpha, int tri_skip, int tri_k, int aout)
{
    constexpr int NW = BN / WN;
    constexpr int MI = WM / 16;
    constexpr int NI = WN / 16;
    constexpr int LDT = 40;
    __shared__ u16 As[BM * LDT];
    __shared__ u16 Bs[BN * LDT];

    const int m0 = blockIdx.y * BM;
    const int n0 = blockIdx.x * BN;
    if (tri_skip && n0 > m0) return;
    A += (long long)blockIdx.z * sA;
    B += (long long)blockIdx.z * sB;

    const int tid = threadIdx.x;
    const int lane = tid & 63;
    const int wave = tid >> 6;
    const int wm0 = (wave / NW) * WM;
    const int wn0 = (wave % NW) * WN;
    const int fr = lane & 15;
    const int fq = lane >> 4;

    f32x4 acc[MI][NI];
    #pragma unroll
    for (int i = 0; i < MI; ++i)
        #pragma unroll
        for (int j = 0; j < NI; ++j) acc[i][j] = (f32x4){0.f, 0.f, 0.f, 0.f};

    int Kend = K;
    if (tri_k) { int kb = m0 + BM; if (kb < Kend) Kend = kb; }

    for (int k0 = 0; k0 < Kend; k0 += 32) {
        #pragma unroll
        for (int c = 0; c < (BM * 4) / 256; ++c) {
            int cid = tid + c * 256;
            int r = cid >> 2, ks = (cid & 3) * 8;
            *(bf16x8*)&As[r * LDT + ks] =
                *(const bf16x8*)(A + (long long)(m0 + r) * K + k0 + ks);
        }
        #pragma unroll
        for (int c = 0; c < (BN * 4) / 256; ++c) {
            int cid = tid + c * 256;
            int r = cid >> 2, ks = (cid & 3) * 8;
            *(bf16x8*)&Bs[r * LDT + ks] =
                *(const bf16x8*)(B + (long long)(n0 + r) * K + k0 + ks);
        }
        __syncthreads();
        bf16x8 af[MI], bfr[NI];
        #pragma unroll
        for (int i = 0; i < MI; ++i)
            af[i] = *(const bf16x8*)&As[(wm0 + i * 16 + fr) * LDT + fq * 8];
        #pragma unroll
        for (int j = 0; j < NI; ++j)
            bfr[j] = *(const bf16x8*)&Bs[(wn0 + j * 16 + fr) * LDT + fq * 8];
        #pragma unroll
        for (int i = 0; i < MI; ++i)
            #pragma unroll
            for (int j = 0; j < NI; ++j)
                acc[i][j] = __builtin_amdgcn_mfma_f32_16x16x32_bf16(
                    af[i], bfr[j], acc[i][j], 0, 0, 0);
        __syncthreads();
    }

    long long cb;
    long long ldc = N;
    if (aout) {   // (B,L,H*D) bf16: z = b*16+h
        cb = (long long)(blockIdx.z >> 4) * 1048576 + (blockIdx.z & 15) * 64;
        ldc = 1024;
    } else {
        cb = (long long)blockIdx.z * sC;
    }
    #pragma unroll
    for (int i = 0; i < MI; ++i)
        #pragma unroll
        for (int j = 0; j < NI; ++j)
            #pragma unroll
            for (int r = 0; r < 4; ++r) {
                int row = m0 + wm0 + i * 16 + fq * 4 + r;
                int col = n0 + wn0 + j * 16 + fr;
                float v = acc[i][j][r] * alpha;
                if (CBF16 || aout)
                    ((u16*)Cv)[cb + (long long)row * ldc + col] = f2b(v);
                else
                    ((float*)Cv)[cb + (long long)row * ldc + col] = v;
            }
}

// ---------------------------------------------------------------------------
__global__ __launch_bounds__(256) void cast_f2b(
    const float* __restrict__ src, u16* __restrict__ dst, int n)
{
    int i = blockIdx.x * 256 + threadIdx.x;
    if (i < n) dst[i] = f2b(src[i]);
}

// ---------------------------------------------------------------------------
// Kerple table: ktab[dist][h] = bf16(-softplus(log_p[h])*log1p(softplus(log_a[h])*dist))
// ---------------------------------------------------------------------------
__global__ __launch_bounds__(256) void kerple_tab(
    const float* __restrict__ log_p, const float* __restrict__ log_a,
    u16* __restrict__ ktab)
{
    int idx = blockIdx.x * 256 + threadIdx.x;   // 16384
    int h = idx & 15, dist = idx >> 4;
    float p = log1pf(__expf(log_p[h]));
    float a = log1pf(__expf(log_a[h]));
    ktab[idx] = f2b(-p * log1pf(a * (float)dist));
}

// ---------------------------------------------------------------------------
// dst[n][m] = bf16(src[m][n]); grid (N/64, M/64)
// ---------------------------------------------------------------------------
__global__ __launch_bounds__(256) void transpose_cast_f2b(
    const float* __restrict__ src, u16* __restrict__ dst, int M, int N)
{
    __shared__ float tile[64][65];
    const int m0 = blockIdx.y * 64, n0 = blockIdx.x * 64;
    const int tid = threadIdx.x;
    #pragma unroll
    for (int c = 0; c < 4; ++c) {
        int f = tid + c * 256;
        int r = f >> 4, cs = (f & 15) * 4;
        float4 v = *(const float4*)&src[(long long)(m0 + r) * N + n0 + cs];
        tile[r][cs] = v.x; tile[r][cs + 1] = v.y;
        tile[r][cs + 2] = v.z; tile[r][cs + 3] = v.w;
    }
    __syncthreads();
    int nl = tid >> 2, ms = (tid & 3) * 16;
    u16 outv[16];
    #pragma unroll
    for (int c = 0; c < 16; ++c) outv[c] = f2b(tile[ms + c][nl]);
    *(bf16x8*)&dst[(long long)(n0 + nl) * M + m0 + ms]     = *(bf16x8*)&outv[0];
    *(bf16x8*)&dst[(long long)(n0 + nl) * M + m0 + ms + 8] = *(bf16x8*)&outv[8];
}

// ---------------------------------------------------------------------------
// v (bh)[1024][64] bf16 -> vT (bh)[64][1024] bf16; grid (16, B*H)
// ---------------------------------------------------------------------------
__global__ __launch_bounds__(256) void vtrans(
    const u16* __restrict__ src, u16* __restrict__ dst)
{
    __shared__ u16 tile[64][65];
    const int bh = blockIdx.y;
    const int l0 = blockIdx.x * 64;
    const int tid = threadIdx.x;
    const u16* s = src + (long long)bh * 65536;
    u16* d = dst + (long long)bh * 65536;
    #pragma unroll
    for (int c = 0; c < 2; ++c) {
        int f = tid + c * 256;
        int r = f >> 3, cs = (f & 7) * 8;
        bf16x8 v = *(const bf16x8*)&s[(l0 + r) * 64 + cs];
        #pragma unroll
        for (int e = 0; e < 8; ++e) tile[r][cs + e] = (u16)v[e];
    }
    __syncthreads();
    int dl = tid >> 2, ls = (tid & 3) * 16;
    u16 outv[16];
    #pragma unroll
    for (int c = 0; c < 16; ++c) outv[c] = tile[ls + c][dl];
    *(bf16x8*)&d[dl * 1024 + l0 + ls]     = *(bf16x8*)&outv[0];
    *(bf16x8*)&d[dl * 1024 + l0 + ls + 8] = *(bf16x8*)&outv[8];
}

// ---------------------------------------------------------------------------
// RoPE + split qkv(B,L,3,H,D) bf16 -> q,k,v (B,H,L,D) bf16
// ---------------------------------------------------------------------------
__global__ __launch_bounds__(256) void rope_split_bf(
    const u16* __restrict__ qkv,
    u16* __restrict__ q, u16* __restrict__ k, u16* __restrict__ v)
{
    int idx = blockIdx.x * 256 + threadIdx.x;
    int d = idx & 63;
    int l = (idx >> 6) & 1023;
    int h = (idx >> 16) & 15;
    int b = idx >> 20;
    const long long src = ((long long)(b * Lv + l) * 3) * 1024 + h * 64 + d;
    int i = d & 31;
    float inv_freq = __expf((float)i * -0.28782313662425574f); // -ln(10000)/32
    float arg = (float)l * inv_freq;
    float c, s;
    __sincosf(arg, &s, &c);
    float x0 = b2f(qkv[src]);
    float xr0 = (d < 32) ? -b2f(qkv[src + 32]) : b2f(qkv[src - 32]);
    q[idx] = f2b(x0 * c + xr0 * s);
    float x1 = b2f(qkv[src + 1024]);
    float xr1 = (d < 32) ? -b2f(qkv[src + 1024 + 32]) : b2f(qkv[src + 1024 - 32]);
    k[idx] = f2b(x1 * c + xr1 * s);
    v[idx] = qkv[src + 2048];
}

// ---------------------------------------------------------------------------
// FUSED kerple + DAPE MLP (MFMA) + causal softmax, in-place on bf16 scores.
// One block per (b, i). Final logits for all 16 heads live in LDS; the only
// global writes are the coalesced final softmax weights (+ zero wedge).
// ---------------------------------------------------------------------------
#define LSTR 1042   // logits row stride (u16): 16 distinct banks across heads

__global__ __launch_bounds__(256) void dape_soft(
    u16* __restrict__ S, const u16* __restrict__ ktab,
    const float* __restrict__ w1, const float* __restrict__ b1,
    const float* __restrict__ w2, const float* __restrict__ b2)
{
    const int i = 1023 - blockIdx.x;         // longest rows first
    const int b = blockIdx.y;

    __shared__ u16 logits[16 * LSTR];        // 33.3 KB
    __shared__ u16 comb[256 * 36];           // 18 KB
    __shared__ u16 hid[4][16 * 36];          // 4.6 KB
    __shared__ float red[16 * 17];
    __shared__ float rmax_s[16], rsum_s[16];

    const int tid = threadIdx.x;
    const int lane = tid & 63;
    const int wave = tid >> 6;
    const int fr = lane & 15;
    const int fq = lane >> 4;

    // weight fragments (registers); B[n=lane&15][k=fq*8+e]
    bf16x8 B1a, B1b, B2f;
    #pragma unroll
    for (int e = 0; e < 8; ++e) {
        int c = fq * 8 + e;
        B1a[e] = (short)f2b(w1[c * 32 + fr]);
        B1b[e] = (short)f2b(w1[c * 32 + 16 + fr]);
        B2f[e] = (short)f2b(w2[c * 16 + fr]);
    }
    const float b1a = b1[fr], b1b = b1[16 + fr], b2v = b2[fr];

    const long long sbase = (long long)b * 16 * 1048576 + (long long)i * 1024;
    const int nchunk = (i >> 8) + 1;

    for (int c = 0; c < nchunk; ++c) {
        const int j = c * 256 + tid;         // always <= 1023
        {   // stage comb[j][0..31]
            u16 row[32];
            #pragma unroll
            for (int h = 0; h < 16; ++h)
                row[h] = S[sbase + (long long)h * 1048576 + j];
            const int dist = (i - j > 0) ? (i - j) : 0;
            *(bf16x8*)&row[16] = *(const bf16x8*)&ktab[dist * 16];
            *(bf16x8*)&row[24] = *(const bf16x8*)&ktab[dist * 16 + 8];
            #pragma unroll
            for (int q = 0; q < 4; ++q)
                *(bf16x8*)&comb[tid * 36 + q * 8] = *(bf16x8*)&row[q * 8];
        }
        __syncthreads();

        for (int t = wave; t < 16; t += 4) {
            const int jt = c * 256 + t * 16;
            if (jt > i) continue;

            bf16x8 A1 = *(const bf16x8*)&comb[(t * 16 + fr) * 36 + fq * 8];
            f32x4 z = (f32x4){0.f, 0.f, 0.f, 0.f};
            f32x4 ac1a = __builtin_amdgcn_mfma_f32_16x16x32_bf16(A1, B1a, z, 0, 0, 0);
            f32x4 ac1b = __builtin_amdgcn_mfma_f32_16x16x32_bf16(A1, B1b, z, 0, 0, 0);

            #pragma unroll
            for (int r = 0; r < 4; ++r) {
                float g0 = gelu_fast(ac1a[r] + b1a);
                float g1 = gelu_fast(ac1b[r] + b1b);
                hid[wave][(fq * 4 + r) * 36 + fr]      = f2b(g0);
                hid[wave][(fq * 4 + r) * 36 + 16 + fr] = f2b(g1);
            }
            bf16x8 A2 = *(const bf16x8*)&hid[wave][fr * 36 + fq * 8];
            f32x4 ac2 = __builtin_amdgcn_mfma_f32_16x16x32_bf16(A2, B2f, z, 0, 0, 0);

            // lane holds h=fr, positions jt+fq*4+r -> LDS logits (masked later)
            #pragma unroll
            for (int r = 0; r < 4; ++r) {
                int jl = t * 16 + fq * 4 + r;
                float scv = b2f(comb[jl * 36 + fr]);
                float kv  = b2f(comb[jl * 36 + 16 + fr]);
                logits[fr * LSTR + jt + fq * 4 + r] = f2b(scv + kv + ac2[r] + b2v);
            }
        }
        __syncthreads();                     // comb reuse + logits complete
    }

    // ---- softmax in LDS: 16 threads per head ----
    const int h = tid >> 4, l = tid & 15;
    float mx = -3.0e38f;
    for (int j = l; j <= i; j += 16) mx = fmaxf(mx, b2f(logits[h * LSTR + j]));
    red[h * 17 + l] = mx;
    __syncthreads();
    if (l == 0) {
        float m2 = red[h * 17];
        #pragma unroll
        for (int t = 1; t < 16; ++t) m2 = fmaxf(m2, red[h * 17 + t]);
        rmax_s[h] = m2;
    }
    __syncthreads();
    {
        const float m2 = rmax_s[h];
        float sm = 0.f;
        for (int j = l; j <= i; j += 16) {
            float e = __expf(b2f(logits[h * LSTR + j]) - m2);
            sm += e;
            logits[h * LSTR + j] = f2b(e);   // store exp for the write pass
        }
        red[h * 17 + l] = sm;
    }
    __syncthreads();
    if (l == 0) {
        float s2 = 0.f;
        #pragma unroll
        for (int t = 0; t < 16; ++t) s2 += red[h * 17 + t];
        rsum_s[h] = s2;
    }
    __syncthreads();

    // ---- coalesced weight write (in-place on S) + zero wedge ----
    const int we = ((i >> 7) + 1) << 7;      // PV K bound
    const int j0 = tid * 4;
    if (j0 < we) {
        #pragma unroll 4
        for (int h2 = 0; h2 < 16; ++h2) {
            const float inv = 1.0f / rsum_s[h2];
            u16 o[4];
            #pragma unroll
            for (int e = 0; e < 4; ++e) {
                int j = j0 + e;
                float v = (j <= i) ? b2f(logits[h2 * LSTR + j]) * inv : 0.f;
                o[e] = f2b(v);
            }
            *(u16x4*)&S[sbase + (long long)h2 * 1048576 + j0] = *(u16x4*)o;
        }
    }
}

// ---------------------------------------------------------------------------
extern "C" void kernel_launch(void* const* d_in, const int* in_sizes, int n_in,
                              void* d_out, int out_size, void* d_ws, size_t ws_size,
                              hipStream_t stream)
{
    const float* x     = (const float*)d_in[0];
    const float* w_qkv = (const float*)d_in[1];
    const float* w_o   = (const float*)d_in[2];
    const float* log_p = (const float*)d_in[3];
    const float* log_a = (const float*)d_in[4];
    const float* w1    = (const float*)d_in[5];
    const float* b1    = (const float*)d_in[6];
    const float* w2    = (const float*)d_in[7];
    const float* b2    = (const float*)d_in[8];
    float* out = (float*)d_out;

    char* p = (char*)d_ws;
    u16* qkv_bf  = (u16*)p;    p += 6291456ll * 2;   // (B,L,3,H,D) bf16
    u16* x_bf    = (u16*)p;    p += 2097152ll * 2;
    u16* wqkvT   = (u16*)p;    p += 3145728ll * 2;   // (3HD, HID)
    u16* woT     = (u16*)p;    p += 1048576ll * 2;   // (HID, HD)
    u16* q_bf    = (u16*)p;    p += 2097152ll * 2;   // (B,H,L,D)
    u16* k_bf    = (u16*)p;    p += 2097152ll * 2;
    u16* v_bf    = (u16*)p;    p += 2097152ll * 2;
    u16* vT      = (u16*)p;    p += 2097152ll * 2;   // (B,H,D,L)
    u16* scores  = (u16*)p;    p += 33554432ll * 2;  // (B,H,L,L) bf16, in-place
    u16* attn_bf = (u16*)p;    p += 2097152ll * 2;   // (B,L,H*D)
    u16* ktab    = (u16*)p;    p += 16384ll * 2;     // kerple[dist][h]

    // casts / transposes / tables
    cast_f2b<<<8192, 256, 0, stream>>>(x, x_bf, 2097152);
    transpose_cast_f2b<<<dim3(48, 16), 256, 0, stream>>>(w_qkv, wqkvT, HIDv, 3 * Hv * Dv);
    transpose_cast_f2b<<<dim3(16, 16), 256, 0, stream>>>(w_o, woT, Hv * Dv, HIDv);
    kerple_tab<<<64, 256, 0, stream>>>(log_p, log_a, ktab);

    // 1. qkv = x @ w_qkv (bf16 out)
    gemm_bt<128, 128, 64, 64, true><<<dim3(24, 16, 1), 256, 0, stream>>>(
        x_bf, wqkvT, qkv_bf, 2048, 3072, 1024, 0, 0, 0, 1.0f, 0, 0, 0);

    // 2. rope + split
    rope_split_bf<<<8192, 256, 0, stream>>>(qkv_bf, q_bf, k_bf, v_bf);
    vtrans<<<dim3(16, 32), 256, 0, stream>>>(v_bf, vT);

    // 3. scores = (q @ k^T)/8, causal tiles only, bf16 out
    gemm_bt<128, 128, 64, 64, true><<<dim3(8, 8, 32), 256, 0, stream>>>(
        q_bf, k_bf, scores, 1024, 1024, 64,
        65536, 65536, 1048576, 0.125f, 1, 0, 0);

    // 4. FUSED kerple + DAPE MLP + softmax (in-place -> weights + wedge)
    dape_soft<<<dim3(1024, 2), 256, 0, stream>>>(
        scores, ktab, w1, b1, w2, b2);

    // 5. attn_bf = weights @ v, written directly to (B,L,H*D) bf16
    gemm_bt<128, 64, 64, 32, false><<<dim3(1, 8, 32), 256, 0, stream>>>(
        scores, vT, attn_bf, 1024, 64, 1024,
        1048576, 65536, 0, 1.0f, 0, 1, 1);

    // 6. out = attn_fl @ w_o  (2048 x 1024 x 1024), 256 blocks
    gemm_bt<128, 64, 64, 32, false><<<dim3(16, 16, 1), 256, 0, stream>>>(
        attn_bf, woT, out, 2048, 1024, 1024, 0, 0, 0, 1.0f, 0, 0, 0);
}

// Round 7
// 269.742 us; speedup vs baseline: 10.3253x; 1.0313x over previous
//
#include <hip/hip_runtime.h>
#include <math.h>

#define Bv 2
#define Lv 1024
#define Hv 16
#define Dv 64
#define HIDv 1024

typedef unsigned short u16;
typedef short bf16x8 __attribute__((ext_vector_type(8)));
typedef unsigned short u16x4 __attribute__((ext_vector_type(4)));
typedef float f32x4 __attribute__((ext_vector_type(4)));

__device__ __forceinline__ u16 f2b(float f) {
    union { float f; unsigned u; } v; v.f = f;
    unsigned r = v.u + 0x7fffu + ((v.u >> 16) & 1u);
    return (u16)(r >> 16);
}
__device__ __forceinline__ float b2f(u16 h) {
    union { unsigned u; float f; } v; v.u = ((unsigned)h) << 16;
    return v.f;
}

// gelu with A&S 7.1.26 erf (max abs err 1.5e-7): ~15 VALU inst vs libm ~60.
__device__ __forceinline__ float gelu_fast(float x) {
    float y = x * 0.70710678118654752f;
    float a = fabsf(y);
    float t = 1.0f / (1.0f + 0.3275911f * a);
    float p = t * (0.254829592f + t * (-0.284496736f +
              t * (1.421413741f + t * (-1.453152027f + t * 1.061405429f))));
    float e = __expf(-a * a);
    float erfv = copysignf(1.0f - p * e, y);
    return 0.5f * x * (1.0f + erfv);
}

// ---------------------------------------------------------------------------
// bf16 MFMA GEMM (LDS-staged): C = alpha * A @ B^T  — used for the two
// K=1024 dense projections (qkv, out).
// ---------------------------------------------------------------------------
template<int BM, int BN, int WM, int WN, bool CBF16>
__global__ __launch_bounds__(256) void gemm_bt(
    const u16* __restrict__ A, const u16* __restrict__ B, void* __restrict__ Cv,
    int M, int N, int K, float alpha)
{
    constexpr int NW = BN / WN;
    constexpr int MI = WM / 16;
    constexpr int NI = WN / 16;
    constexpr int LDT = 40;
    __shared__ u16 As[BM * LDT];
    __shared__ u16 Bs[BN * LDT];

    const int m0 = blockIdx.y * BM;
    const int n0 = blockIdx.x * BN;

    const int tid = threadIdx.x;
    const int lane = tid & 63;
    const int wave = tid >> 6;
    const int wm0 = (wave / NW) * WM;
    const int wn0 = (wave % NW) * WN;
    const int fr = lane & 15;
    const int fq = lane >> 4;

    f32x4 acc[MI][NI];
    #pragma unroll
    for (int i = 0; i < MI; ++i)
        #pragma unroll
        for (int j = 0; j < NI; ++j) acc[i][j] = (f32x4){0.f, 0.f, 0.f, 0.f};

    for (int k0 = 0; k0 < K; k0 += 32) {
        #pragma unroll
        for (int c = 0; c < (BM * 4) / 256; ++c) {
            int cid = tid + c * 256;
            int r = cid >> 2, ks = (cid & 3) * 8;
            *(bf16x8*)&As[r * LDT + ks] =
                *(const bf16x8*)(A + (long long)(m0 + r) * K + k0 + ks);
        }
        #pragma unroll
        for (int c = 0; c < (BN * 4) / 256; ++c) {
            int cid = tid + c * 256;
            int r = cid >> 2, ks = (cid & 3) * 8;
            *(bf16x8*)&Bs[r * LDT + ks] =
                *(const bf16x8*)(B + (long long)(n0 + r) * K + k0 + ks);
        }
        __syncthreads();
        bf16x8 af[MI], bfr[NI];
        #pragma unroll
        for (int i = 0; i < MI; ++i)
            af[i] = *(const bf16x8*)&As[(wm0 + i * 16 + fr) * LDT + fq * 8];
        #pragma unroll
        for (int j = 0; j < NI; ++j)
            bfr[j] = *(const bf16x8*)&Bs[(wn0 + j * 16 + fr) * LDT + fq * 8];
        #pragma unroll
        for (int i = 0; i < MI; ++i)
            #pragma unroll
            for (int j = 0; j < NI; ++j)
                acc[i][j] = __builtin_amdgcn_mfma_f32_16x16x32_bf16(
                    af[i], bfr[j], acc[i][j], 0, 0, 0);
        __syncthreads();
    }

    #pragma unroll
    for (int i = 0; i < MI; ++i)
        #pragma unroll
        for (int j = 0; j < NI; ++j)
            #pragma unroll
            for (int r = 0; r < 4; ++r) {
                int row = m0 + wm0 + i * 16 + fq * 4 + r;
                int col = n0 + wn0 + j * 16 + fr;
                float v = acc[i][j][r] * alpha;
                if (CBF16) ((u16*)Cv)[(long long)row * N + col] = f2b(v);
                else      ((float*)Cv)[(long long)row * N + col] = v;
            }
}

// ---------------------------------------------------------------------------
// QK^T direct-from-global (K=64 fits in fragments; no LDS, no barriers).
// grid (8, 8, B*H); 128x128 block tile, 4 waves of 64x64.
// ---------------------------------------------------------------------------
__global__ __launch_bounds__(256) void qk_direct(
    const u16* __restrict__ Q, const u16* __restrict__ K, u16* __restrict__ S)
{
    const int m0 = blockIdx.y * 128;
    const int n0 = blockIdx.x * 128;
    if (n0 > m0) return;                      // causal upper tiles
    const u16* A = Q + (long long)blockIdx.z * 65536;
    const u16* B = K + (long long)blockIdx.z * 65536;
    u16* C = S + (long long)blockIdx.z * 1048576;

    const int lane = threadIdx.x & 63;
    const int wave = threadIdx.x >> 6;
    const int wm0 = (wave >> 1) * 64;
    const int wn0 = (wave & 1) * 64;
    const int fr = lane & 15;
    const int fq = lane >> 4;

    bf16x8 af[4][2], bfr[4][2];
    #pragma unroll
    for (int i = 0; i < 4; ++i)
        #pragma unroll
        for (int p = 0; p < 2; ++p) {
            af[i][p]  = *(const bf16x8*)&A[(m0 + wm0 + i * 16 + fr) * 64 + p * 32 + fq * 8];
            bfr[i][p] = *(const bf16x8*)&B[(n0 + wn0 + i * 16 + fr) * 64 + p * 32 + fq * 8];
        }

    f32x4 acc[4][4];
    #pragma unroll
    for (int i = 0; i < 4; ++i)
        #pragma unroll
        for (int j = 0; j < 4; ++j) acc[i][j] = (f32x4){0.f, 0.f, 0.f, 0.f};

    #pragma unroll
    for (int p = 0; p < 2; ++p)
        #pragma unroll
        for (int i = 0; i < 4; ++i)
            #pragma unroll
            for (int j = 0; j < 4; ++j)
                acc[i][j] = __builtin_amdgcn_mfma_f32_16x16x32_bf16(
                    af[i][p], bfr[j][p], acc[i][j], 0, 0, 0);

    #pragma unroll
    for (int i = 0; i < 4; ++i)
        #pragma unroll
        for (int j = 0; j < 4; ++j)
            #pragma unroll
            for (int r = 0; r < 4; ++r) {
                int row = m0 + wm0 + i * 16 + fq * 4 + r;
                int col = n0 + wn0 + j * 16 + fr;
                C[(long long)row * 1024 + col] = f2b(acc[i][j][r] * 0.125f);
            }
}

// ---------------------------------------------------------------------------
// PV direct-from-global (triangular K, no LDS, no barriers).
// grid (16, B*H); 64-row tile, 4 waves of 32x32; K bounded at m0+64.
// Writes bf16 directly into (B,L,H*D).
// ---------------------------------------------------------------------------
__global__ __launch_bounds__(256) void pv_direct(
    const u16* __restrict__ W, const u16* __restrict__ VT, u16* __restrict__ O)
{
    const int m0 = blockIdx.x * 64;
    const int bh = blockIdx.y;
    const u16* A = W + (long long)bh * 1048576;
    const u16* B = VT + (long long)bh * 65536;
    const int b = bh >> 4, h = bh & 15;

    const int lane = threadIdx.x & 63;
    const int wave = threadIdx.x >> 6;
    const int wm0 = (wave >> 1) * 32;
    const int wn0 = (wave & 1) * 32;
    const int fr = lane & 15;
    const int fq = lane >> 4;

    f32x4 acc[2][2];
    #pragma unroll
    for (int i = 0; i < 2; ++i)
        #pragma unroll
        for (int j = 0; j < 2; ++j) acc[i][j] = (f32x4){0.f, 0.f, 0.f, 0.f};

    const int Kend = m0 + 64;                 // weights are zero-padded past i
    for (int k0 = 0; k0 < Kend; k0 += 64) {   // 2 k-chunks per iter
        bf16x8 af[2][2], bfr[2][2];
        #pragma unroll
        for (int p = 0; p < 2; ++p) {
            #pragma unroll
            for (int i = 0; i < 2; ++i)
                af[p][i] = *(const bf16x8*)&A[(m0 + wm0 + i * 16 + fr) * 1024 + k0 + p * 32 + fq * 8];
            #pragma unroll
            for (int j = 0; j < 2; ++j)
                bfr[p][j] = *(const bf16x8*)&B[(wn0 + j * 16 + fr) * 1024 + k0 + p * 32 + fq * 8];
        }
        #pragma unroll
        for (int p = 0; p < 2; ++p)
            #pragma unroll
            for (int i = 0; i < 2; ++i)
                #pragma unroll
                for (int j = 0; j < 2; ++j)
                    acc[i][j] = __builtin_amdgcn_mfma_f32_16x16x32_bf16(
                        af[p][i], bfr[p][j], acc[i][j], 0, 0, 0);
    }

    const long long ob = (long long)b * 1048576 + h * 64;
    #pragma unroll
    for (int i = 0; i < 2; ++i)
        #pragma unroll
        for (int j = 0; j < 2; ++j)
            #pragma unroll
            for (int r = 0; r < 4; ++r) {
                int row = m0 + wm0 + i * 16 + fq * 4 + r;
                int col = wn0 + j * 16 + fr;
                O[ob + (long long)row * 1024 + col] = f2b(acc[i][j][r]);
            }
}

// ---------------------------------------------------------------------------
__global__ __launch_bounds__(256) void cast_f2b(
    const float* __restrict__ src, u16* __restrict__ dst, int n)
{
    int i = blockIdx.x * 256 + threadIdx.x;
    if (i < n) dst[i] = f2b(src[i]);
}

// ---------------------------------------------------------------------------
// Kerple table: ktab[dist][h] = bf16(-softplus(log_p[h])*log1p(softplus(log_a[h])*dist))
// ---------------------------------------------------------------------------
__global__ __launch_bounds__(256) void kerple_tab(
    const float* __restrict__ log_p, const float* __restrict__ log_a,
    u16* __restrict__ ktab)
{
    int idx = blockIdx.x * 256 + threadIdx.x;   // 16384
    int h = idx & 15, dist = idx >> 4;
    float p = log1pf(__expf(log_p[h]));
    float a = log1pf(__expf(log_a[h]));
    ktab[idx] = f2b(-p * log1pf(a * (float)dist));
}

// ---------------------------------------------------------------------------
// dst[n][m] = bf16(src[m][n]); grid (N/64, M/64)
// ---------------------------------------------------------------------------
__global__ __launch_bounds__(256) void transpose_cast_f2b(
    const float* __restrict__ src, u16* __restrict__ dst, int M, int N)
{
    __shared__ float tile[64][65];
    const int m0 = blockIdx.y * 64, n0 = blockIdx.x * 64;
    const int tid = threadIdx.x;
    #pragma unroll
    for (int c = 0; c < 4; ++c) {
        int f = tid + c * 256;
        int r = f >> 4, cs = (f & 15) * 4;
        float4 v = *(const float4*)&src[(long long)(m0 + r) * N + n0 + cs];
        tile[r][cs] = v.x; tile[r][cs + 1] = v.y;
        tile[r][cs + 2] = v.z; tile[r][cs + 3] = v.w;
    }
    __syncthreads();
    int nl = tid >> 2, ms = (tid & 3) * 16;
    u16 outv[16];
    #pragma unroll
    for (int c = 0; c < 16; ++c) outv[c] = f2b(tile[ms + c][nl]);
    *(bf16x8*)&dst[(long long)(n0 + nl) * M + m0 + ms]     = *(bf16x8*)&outv[0];
    *(bf16x8*)&dst[(long long)(n0 + nl) * M + m0 + ms + 8] = *(bf16x8*)&outv[8];
}

// ---------------------------------------------------------------------------
// v (bh)[1024][64] bf16 -> vT (bh)[64][1024] bf16; grid (16, B*H)
// ---------------------------------------------------------------------------
__global__ __launch_bounds__(256) void vtrans(
    const u16* __restrict__ src, u16* __restrict__ dst)
{
    __shared__ u16 tile[64][65];
    const int bh = blockIdx.y;
    const int l0 = blockIdx.x * 64;
    const int tid = threadIdx.x;
    const u16* s = src + (long long)bh * 65536;
    u16* d = dst + (long long)bh * 65536;
    #pragma unroll
    for (int c = 0; c < 2; ++c) {
        int f = tid + c * 256;
        int r = f >> 3, cs = (f & 7) * 8;
        bf16x8 v = *(const bf16x8*)&s[(l0 + r) * 64 + cs];
        #pragma unroll
        for (int e = 0; e < 8; ++e) tile[r][cs + e] = (u16)v[e];
    }
    __syncthreads();
    int dl = tid >> 2, ls = (tid & 3) * 16;
    u16 outv[16];
    #pragma unroll
    for (int c = 0; c < 16; ++c) outv[c] = tile[ls + c][dl];
    *(bf16x8*)&d[dl * 1024 + l0 + ls]     = *(bf16x8*)&outv[0];
    *(bf16x8*)&d[dl * 1024 + l0 + ls + 8] = *(bf16x8*)&outv[8];
}

// ---------------------------------------------------------------------------
// RoPE + split qkv(B,L,3,H,D) bf16 -> q,k,v (B,H,L,D) bf16
// ---------------------------------------------------------------------------
__global__ __launch_bounds__(256) void rope_split_bf(
    const u16* __restrict__ qkv,
    u16* __restrict__ q, u16* __restrict__ k, u16* __restrict__ v)
{
    int idx = blockIdx.x * 256 + threadIdx.x;
    int d = idx & 63;
    int l = (idx >> 6) & 1023;
    int h = (idx >> 16) & 15;
    int b = idx >> 20;
    const long long src = ((long long)(b * Lv + l) * 3) * 1024 + h * 64 + d;
    int i = d & 31;
    float inv_freq = __expf((float)i * -0.28782313662425574f); // -ln(10000)/32
    float arg = (float)l * inv_freq;
    float c, s;
    __sincosf(arg, &s, &c);
    float x0 = b2f(qkv[src]);
    float xr0 = (d < 32) ? -b2f(qkv[src + 32]) : b2f(qkv[src - 32]);
    q[idx] = f2b(x0 * c + xr0 * s);
    float x1 = b2f(qkv[src + 1024]);
    float xr1 = (d < 32) ? -b2f(qkv[src + 1024 + 32]) : b2f(qkv[src + 1024 - 32]);
    k[idx] = f2b(x1 * c + xr1 * s);
    v[idx] = qkv[src + 2048];
}

// ---------------------------------------------------------------------------
// FUSED kerple + DAPE MLP (MFMA) + causal softmax, in-place on bf16 scores.
// One block per (b, i). Logits in LDS; softmax is wave-autonomous
// (4 heads per wave, shuffle reductions, exp kept in registers, zero extra
// barriers), final weights written coalesced incl. the zero wedge.
// ---------------------------------------------------------------------------
#define LSTR 1044   // logits row stride (u16): mult of 4 for b64 alignment

__global__ __launch_bounds__(256) void dape_soft(
    u16* __restrict__ S, const u16* __restrict__ ktab,
    const float* __restrict__ w1, const float* __restrict__ b1,
    const float* __restrict__ w2, const float* __restrict__ b2)
{
    const int i = 1023 - blockIdx.x;         // longest rows first
    const int b = blockIdx.y;

    __shared__ u16 logits[16 * LSTR];        // 33.4 KB
    __shared__ u16 comb[256 * 36];           // 18 KB
    __shared__ u16 hid[4][16 * 36];          // 4.6 KB

    const int tid = threadIdx.x;
    const int lane = tid & 63;
    const int wave = tid >> 6;
    const int fr = lane & 15;
    const int fq = lane >> 4;

    // weight fragments (registers); B[n=lane&15][k=fq*8+e]
    bf16x8 B1a, B1b, B2f;
    #pragma unroll
    for (int e = 0; e < 8; ++e) {
        int c = fq * 8 + e;
        B1a[e] = (short)f2b(w1[c * 32 + fr]);
        B1b[e] = (short)f2b(w1[c * 32 + 16 + fr]);
        B2f[e] = (short)f2b(w2[c * 16 + fr]);
    }
    const float b1a = b1[fr], b1b = b1[16 + fr], b2v = b2[fr];

    const long long sbase = (long long)b * 16 * 1048576 + (long long)i * 1024;
    const int nchunk = (i >> 8) + 1;

    for (int c = 0; c < nchunk; ++c) {
        const int j = c * 256 + tid;
        {   // stage comb[j][0..31]
            u16 row[32];
            #pragma unroll
            for (int h = 0; h < 16; ++h)
                row[h] = S[sbase + (long long)h * 1048576 + j];
            const int dist = (i - j > 0) ? (i - j) : 0;
            *(bf16x8*)&row[16] = *(const bf16x8*)&ktab[dist * 16];
            *(bf16x8*)&row[24] = *(const bf16x8*)&ktab[dist * 16 + 8];
            #pragma unroll
            for (int q = 0; q < 4; ++q)
                *(bf16x8*)&comb[tid * 36 + q * 8] = *(bf16x8*)&row[q * 8];
        }
        __syncthreads();

        for (int t = wave; t < 16; t += 4) {
            const int jt = c * 256 + t * 16;
            if (jt > i) continue;

            bf16x8 A1 = *(const bf16x8*)&comb[(t * 16 + fr) * 36 + fq * 8];
            f32x4 z = (f32x4){0.f, 0.f, 0.f, 0.f};
            f32x4 ac1a = __builtin_amdgcn_mfma_f32_16x16x32_bf16(A1, B1a, z, 0, 0, 0);
            f32x4 ac1b = __builtin_amdgcn_mfma_f32_16x16x32_bf16(A1, B1b, z, 0, 0, 0);

            #pragma unroll
            for (int r = 0; r < 4; ++r) {
                float g0 = gelu_fast(ac1a[r] + b1a);
                float g1 = gelu_fast(ac1b[r] + b1b);
                hid[wave][(fq * 4 + r) * 36 + fr]      = f2b(g0);
                hid[wave][(fq * 4 + r) * 36 + 16 + fr] = f2b(g1);
            }
            bf16x8 A2 = *(const bf16x8*)&hid[wave][fr * 36 + fq * 8];
            f32x4 ac2 = __builtin_amdgcn_mfma_f32_16x16x32_bf16(A2, B2f, z, 0, 0, 0);

            #pragma unroll
            for (int r = 0; r < 4; ++r) {
                int jl = t * 16 + fq * 4 + r;
                float scv = b2f(comb[jl * 36 + fr]);
                float kv  = b2f(comb[jl * 36 + 16 + fr]);
                logits[fr * LSTR + jt + fq * 4 + r] = f2b(scv + kv + ac2[r] + b2v);
            }
        }
        __syncthreads();                     // comb reuse + logits complete
    }

    // ---- wave-autonomous softmax: wave handles heads {wave, wave+4, ...} ----
    const int we = ((i >> 7) + 1) << 7;      // PV K bound (zero wedge end)
    for (int hh = wave; hh < 16; hh += 4) {
        float vals[16];
        float mx = -3.0e38f;
        #pragma unroll
        for (int s = 0; s < 4; ++s) {
            u16x4 r4 = *(const u16x4*)&logits[hh * LSTR + lane * 4 + 256 * s];
            #pragma unroll
            for (int e = 0; e < 4; ++e) {
                int j = lane * 4 + 256 * s + e;
                float v = (j <= i) ? b2f(r4[e]) : -3.0e38f;
                vals[s * 4 + e] = v;
                mx = fmaxf(mx, v);
            }
        }
        #pragma unroll
        for (int off = 1; off < 64; off <<= 1)
            mx = fmaxf(mx, __shfl_xor(mx, off));
        float sm = 0.f;
        #pragma unroll
        for (int e = 0; e < 16; ++e) {
            float ev = (vals[e] > -1.0e37f) ? __expf(vals[e] - mx) : 0.f;
            vals[e] = ev;
            sm += ev;
        }
        #pragma unroll
        for (int off = 1; off < 64; off <<= 1)
            sm += __shfl_xor(sm, off);
        const float inv = 1.0f / sm;
        const long long hb = sbase + (long long)hh * 1048576;
        #pragma unroll
        for (int s = 0; s < 4; ++s) {
            int j0v = lane * 4 + 256 * s;
            if (j0v < we) {
                u16 o[4];
                #pragma unroll
                for (int e = 0; e < 4; ++e) o[e] = f2b(vals[s * 4 + e] * inv);
                *(u16x4*)&S[hb + j0v] = *(u16x4*)o;
            }
        }
    }
}

// ---------------------------------------------------------------------------
extern "C" void kernel_launch(void* const* d_in, const int* in_sizes, int n_in,
                              void* d_out, int out_size, void* d_ws, size_t ws_size,
                              hipStream_t stream)
{
    const float* x     = (const float*)d_in[0];
    const float* w_qkv = (const float*)d_in[1];
    const float* w_o   = (const float*)d_in[2];
    const float* log_p = (const float*)d_in[3];
    const float* log_a = (const float*)d_in[4];
    const float* w1    = (const float*)d_in[5];
    const float* b1    = (const float*)d_in[6];
    const float* w2    = (const float*)d_in[7];
    const float* b2    = (const float*)d_in[8];
    float* out = (float*)d_out;

    char* p = (char*)d_ws;
    u16* qkv_bf  = (u16*)p;    p += 6291456ll * 2;   // (B,L,3,H,D) bf16
    u16* x_bf    = (u16*)p;    p += 2097152ll * 2;
    u16* wqkvT   = (u16*)p;    p += 3145728ll * 2;   // (3HD, HID)
    u16* woT     = (u16*)p;    p += 1048576ll * 2;   // (HID, HD)
    u16* q_bf    = (u16*)p;    p += 2097152ll * 2;   // (B,H,L,D)
    u16* k_bf    = (u16*)p;    p += 2097152ll * 2;
    u16* v_bf    = (u16*)p;    p += 2097152ll * 2;
    u16* vT      = (u16*)p;    p += 2097152ll * 2;   // (B,H,D,L)
    u16* scores  = (u16*)p;    p += 33554432ll * 2;  // (B,H,L,L) bf16, in-place
    u16* attn_bf = (u16*)p;    p += 2097152ll * 2;   // (B,L,H*D)
    u16* ktab    = (u16*)p;    p += 16384ll * 2;     // kerple[dist][h]

    // casts / transposes / tables
    cast_f2b<<<8192, 256, 0, stream>>>(x, x_bf, 2097152);
    transpose_cast_f2b<<<dim3(48, 16), 256, 0, stream>>>(w_qkv, wqkvT, HIDv, 3 * Hv * Dv);
    transpose_cast_f2b<<<dim3(16, 16), 256, 0, stream>>>(w_o, woT, Hv * Dv, HIDv);
    kerple_tab<<<64, 256, 0, stream>>>(log_p, log_a, ktab);

    // 1. qkv = x @ w_qkv (bf16 out)
    gemm_bt<128, 128, 64, 64, true><<<dim3(24, 16, 1), 256, 0, stream>>>(
        x_bf, wqkvT, qkv_bf, 2048, 3072, 1024, 1.0f);

    // 2. rope + split
    rope_split_bf<<<8192, 256, 0, stream>>>(qkv_bf, q_bf, k_bf, v_bf);
    vtrans<<<dim3(16, 32), 256, 0, stream>>>(v_bf, vT);

    // 3. scores = (q @ k^T)/8, direct-from-global, causal tiles only
    qk_direct<<<dim3(8, 8, 32), 256, 0, stream>>>(q_bf, k_bf, scores);

    // 4. FUSED kerple + DAPE MLP + softmax (in-place -> weights + wedge)
    dape_soft<<<dim3(1024, 2), 256, 0, stream>>>(
        scores, ktab, w1, b1, w2, b2);

    // 5. attn_bf = weights @ v, direct-from-global, triangular K
    pv_direct<<<dim3(16, 32), 256, 0, stream>>>(scores, vT, attn_bf);

    // 6. out = attn_fl @ w_o  (2048 x 1024 x 1024), 256 blocks
    gemm_bt<128, 64, 64, 32, false><<<dim3(16, 16, 1), 256, 0, stream>>>(
        attn_bf, woT, out, 2048, 1024, 1024, 1.0f);
}

// Round 8
// 259.694 us; speedup vs baseline: 10.7248x; 1.0387x over previous
//
#include <hip/hip_runtime.h>
#include <math.h>

#define Bv 2
#define Lv 1024
#define Hv 16
#define Dv 64
#define HIDv 1024

typedef unsigned short u16;
typedef short bf16x8 __attribute__((ext_vector_type(8)));
typedef unsigned short u16x4 __attribute__((ext_vector_type(4)));
typedef float f32x4 __attribute__((ext_vector_type(4)));

__device__ __forceinline__ u16 f2b(float f) {
    union { float f; unsigned u; } v; v.f = f;
    unsigned r = v.u + 0x7fffu + ((v.u >> 16) & 1u);
    return (u16)(r >> 16);
}
__device__ __forceinline__ float b2f(u16 h) {
    union { unsigned u; float f; } v; v.u = ((unsigned)h) << 16;
    return v.f;
}

// async global->LDS, 16B per lane. HW semantics: wave-uniform base + lane*16;
// our per-lane lds ptrs are exactly base+lane*16 in issue order.
__device__ __forceinline__ void gl2lds16(const u16* g, u16* l) {
    __builtin_amdgcn_global_load_lds(
        (const __attribute__((address_space(1))) unsigned int*)g,
        (__attribute__((address_space(3))) unsigned int*)l,
        16, 0, 0);
}

// gelu with A&S 7.1.26 erf (max abs err 1.5e-7): ~15 VALU inst vs libm ~60.
__device__ __forceinline__ float gelu_fast(float x) {
    float y = x * 0.70710678118654752f;
    float a = fabsf(y);
    float t = 1.0f / (1.0f + 0.3275911f * a);
    float p = t * (0.254829592f + t * (-0.284496736f +
              t * (1.421413741f + t * (-1.453152027f + t * 1.061405429f))));
    float e = __expf(-a * a);
    float erfv = copysignf(1.0f - p * e, y);
    return 0.5f * x * (1.0f + erfv);
}

// ---------------------------------------------------------------------------
// bf16 MFMA GEMM with global_load_lds staging: C = alpha * A @ B^T
// A: MxK bf16 row-major; B: NxK bf16 row-major; C: MxN.
// LDS tiles are contiguous [rows][32] u16 (64B rows) — no padding, matching
// the wave-uniform-base + lane*16 order of global_load_lds.
// ---------------------------------------------------------------------------
template<int BM, int BN, int WM, int WN, bool CBF16>
__global__ __launch_bounds__(256) void gemm_bt(
    const u16* __restrict__ A, const u16* __restrict__ B, void* __restrict__ Cv,
    int M, int N, int K, float alpha)
{
    constexpr int NW = BN / WN;
    constexpr int MI = WM / 16;
    constexpr int NI = WN / 16;
    __shared__ u16 As[BM * 32];
    __shared__ u16 Bs[BN * 32];

    const int m0 = blockIdx.y * BM;
    const int n0 = blockIdx.x * BN;

    const int tid = threadIdx.x;
    const int lane = tid & 63;
    const int wave = tid >> 6;
    const int wm0 = (wave / NW) * WM;
    const int wn0 = (wave % NW) * WN;
    const int fr = lane & 15;
    const int fq = lane >> 4;

    f32x4 acc[MI][NI];
    #pragma unroll
    for (int i = 0; i < MI; ++i)
        #pragma unroll
        for (int j = 0; j < NI; ++j) acc[i][j] = (f32x4){0.f, 0.f, 0.f, 0.f};

    for (int k0 = 0; k0 < K; k0 += 32) {
        #pragma unroll
        for (int it = 0; it < BM / 64; ++it) {
            int cid = tid + it * 256;          // 16B chunk id
            int r = cid >> 2, ch = cid & 3;
            gl2lds16(A + (long long)(m0 + r) * K + k0 + ch * 8, &As[cid * 8]);
        }
        #pragma unroll
        for (int it = 0; it < BN / 64; ++it) {
            int cid = tid + it * 256;
            int r = cid >> 2, ch = cid & 3;
            gl2lds16(B + (long long)(n0 + r) * K + k0 + ch * 8, &Bs[cid * 8]);
        }
        __syncthreads();                       // drains vmcnt (async LDS)
        bf16x8 af[MI], bfr[NI];
        #pragma unroll
        for (int i = 0; i < MI; ++i)
            af[i] = *(const bf16x8*)&As[(wm0 + i * 16 + fr) * 32 + fq * 8];
        #pragma unroll
        for (int j = 0; j < NI; ++j)
            bfr[j] = *(const bf16x8*)&Bs[(wn0 + j * 16 + fr) * 32 + fq * 8];
        #pragma unroll
        for (int i = 0; i < MI; ++i)
            #pragma unroll
            for (int j = 0; j < NI; ++j)
                acc[i][j] = __builtin_amdgcn_mfma_f32_16x16x32_bf16(
                    af[i], bfr[j], acc[i][j], 0, 0, 0);
        __syncthreads();
    }

    #pragma unroll
    for (int i = 0; i < MI; ++i)
        #pragma unroll
        for (int j = 0; j < NI; ++j)
            #pragma unroll
            for (int r = 0; r < 4; ++r) {
                int row = m0 + wm0 + i * 16 + fq * 4 + r;
                int col = n0 + wn0 + j * 16 + fr;
                float v = acc[i][j][r] * alpha;
                if (CBF16) ((u16*)Cv)[(long long)row * N + col] = f2b(v);
                else      ((float*)Cv)[(long long)row * N + col] = v;
            }
}

// ---------------------------------------------------------------------------
// QK^T direct-from-global (K=64 fits in fragments; no LDS, no barriers).
// grid (8, 8, B*H); 128x128 block tile, 4 waves of 64x64.
// ---------------------------------------------------------------------------
__global__ __launch_bounds__(256) void qk_direct(
    const u16* __restrict__ Q, const u16* __restrict__ K, u16* __restrict__ S)
{
    const int m0 = blockIdx.y * 128;
    const int n0 = blockIdx.x * 128;
    if (n0 > m0) return;                      // causal upper tiles
    const u16* A = Q + (long long)blockIdx.z * 65536;
    const u16* B = K + (long long)blockIdx.z * 65536;
    u16* C = S + (long long)blockIdx.z * 1048576;

    const int lane = threadIdx.x & 63;
    const int wave = threadIdx.x >> 6;
    const int wm0 = (wave >> 1) * 64;
    const int wn0 = (wave & 1) * 64;
    const int fr = lane & 15;
    const int fq = lane >> 4;

    bf16x8 af[4][2], bfr[4][2];
    #pragma unroll
    for (int i = 0; i < 4; ++i)
        #pragma unroll
        for (int p = 0; p < 2; ++p) {
            af[i][p]  = *(const bf16x8*)&A[(m0 + wm0 + i * 16 + fr) * 64 + p * 32 + fq * 8];
            bfr[i][p] = *(const bf16x8*)&B[(n0 + wn0 + i * 16 + fr) * 64 + p * 32 + fq * 8];
        }

    f32x4 acc[4][4];
    #pragma unroll
    for (int i = 0; i < 4; ++i)
        #pragma unroll
        for (int j = 0; j < 4; ++j) acc[i][j] = (f32x4){0.f, 0.f, 0.f, 0.f};

    #pragma unroll
    for (int p = 0; p < 2; ++p)
        #pragma unroll
        for (int i = 0; i < 4; ++i)
            #pragma unroll
            for (int j = 0; j < 4; ++j)
                acc[i][j] = __builtin_amdgcn_mfma_f32_16x16x32_bf16(
                    af[i][p], bfr[j][p], acc[i][j], 0, 0, 0);

    #pragma unroll
    for (int i = 0; i < 4; ++i)
        #pragma unroll
        for (int j = 0; j < 4; ++j)
            #pragma unroll
            for (int r = 0; r < 4; ++r) {
                int row = m0 + wm0 + i * 16 + fq * 4 + r;
                int col = n0 + wn0 + j * 16 + fr;
                C[(long long)row * 1024 + col] = f2b(acc[i][j][r] * 0.125f);
            }
}

// ---------------------------------------------------------------------------
// PV direct-from-global (triangular K, no LDS, no barriers).
// grid (16, B*H); 64-row tile, 4 waves of 32x32; K bounded at m0+64.
// Writes bf16 directly into (B,L,H*D).
// ---------------------------------------------------------------------------
__global__ __launch_bounds__(256) void pv_direct(
    const u16* __restrict__ W, const u16* __restrict__ VT, u16* __restrict__ O)
{
    const int m0 = blockIdx.x * 64;
    const int bh = blockIdx.y;
    const u16* A = W + (long long)bh * 1048576;
    const u16* B = VT + (long long)bh * 65536;
    const int b = bh >> 4, h = bh & 15;

    const int lane = threadIdx.x & 63;
    const int wave = threadIdx.x >> 6;
    const int wm0 = (wave >> 1) * 32;
    const int wn0 = (wave & 1) * 32;
    const int fr = lane & 15;
    const int fq = lane >> 4;

    f32x4 acc[2][2];
    #pragma unroll
    for (int i = 0; i < 2; ++i)
        #pragma unroll
        for (int j = 0; j < 2; ++j) acc[i][j] = (f32x4){0.f, 0.f, 0.f, 0.f};

    const int Kend = m0 + 64;                 // weights zero-padded past i
    for (int k0 = 0; k0 < Kend; k0 += 64) {
        bf16x8 af[2][2], bfr[2][2];
        #pragma unroll
        for (int p = 0; p < 2; ++p) {
            #pragma unroll
            for (int i = 0; i < 2; ++i)
                af[p][i] = *(const bf16x8*)&A[(m0 + wm0 + i * 16 + fr) * 1024 + k0 + p * 32 + fq * 8];
            #pragma unroll
            for (int j = 0; j < 2; ++j)
                bfr[p][j] = *(const bf16x8*)&B[(wn0 + j * 16 + fr) * 1024 + k0 + p * 32 + fq * 8];
        }
        #pragma unroll
        for (int p = 0; p < 2; ++p)
            #pragma unroll
            for (int i = 0; i < 2; ++i)
                #pragma unroll
                for (int j = 0; j < 2; ++j)
                    acc[i][j] = __builtin_amdgcn_mfma_f32_16x16x32_bf16(
                        af[p][i], bfr[p][j], acc[i][j], 0, 0, 0);
    }

    const long long ob = (long long)b * 1048576 + h * 64;
    #pragma unroll
    for (int i = 0; i < 2; ++i)
        #pragma unroll
        for (int j = 0; j < 2; ++j)
            #pragma unroll
            for (int r = 0; r < 4; ++r) {
                int row = m0 + wm0 + i * 16 + fq * 4 + r;
                int col = wn0 + j * 16 + fr;
                O[ob + (long long)row * 1024 + col] = f2b(acc[i][j][r]);
            }
}

// ---------------------------------------------------------------------------
__global__ __launch_bounds__(256) void cast_f2b(
    const float* __restrict__ src, u16* __restrict__ dst, int n)
{
    int i = blockIdx.x * 256 + threadIdx.x;
    if (i < n) dst[i] = f2b(src[i]);
}

// ---------------------------------------------------------------------------
// Kerple table: ktab[dist][h] = bf16(-softplus(log_p[h])*log1p(softplus(log_a[h])*dist))
// ---------------------------------------------------------------------------
__global__ __launch_bounds__(256) void kerple_tab(
    const float* __restrict__ log_p, const float* __restrict__ log_a,
    u16* __restrict__ ktab)
{
    int idx = blockIdx.x * 256 + threadIdx.x;   // 16384
    int h = idx & 15, dist = idx >> 4;
    float p = log1pf(__expf(log_p[h]));
    float a = log1pf(__expf(log_a[h]));
    ktab[idx] = f2b(-p * log1pf(a * (float)dist));
}

// ---------------------------------------------------------------------------
// dst[n][m] = bf16(src[m][n]); grid (N/64, M/64)
// ---------------------------------------------------------------------------
__global__ __launch_bounds__(256) void transpose_cast_f2b(
    const float* __restrict__ src, u16* __restrict__ dst, int M, int N)
{
    __shared__ float tile[64][65];
    const int m0 = blockIdx.y * 64, n0 = blockIdx.x * 64;
    const int tid = threadIdx.x;
    #pragma unroll
    for (int c = 0; c < 4; ++c) {
        int f = tid + c * 256;
        int r = f >> 4, cs = (f & 15) * 4;
        float4 v = *(const float4*)&src[(long long)(m0 + r) * N + n0 + cs];
        tile[r][cs] = v.x; tile[r][cs + 1] = v.y;
        tile[r][cs + 2] = v.z; tile[r][cs + 3] = v.w;
    }
    __syncthreads();
    int nl = tid >> 2, ms = (tid & 3) * 16;
    u16 outv[16];
    #pragma unroll
    for (int c = 0; c < 16; ++c) outv[c] = f2b(tile[ms + c][nl]);
    *(bf16x8*)&dst[(long long)(n0 + nl) * M + m0 + ms]     = *(bf16x8*)&outv[0];
    *(bf16x8*)&dst[(long long)(n0 + nl) * M + m0 + ms + 8] = *(bf16x8*)&outv[8];
}

// ---------------------------------------------------------------------------
// v (bh)[1024][64] bf16 -> vT (bh)[64][1024] bf16; grid (16, B*H)
// ---------------------------------------------------------------------------
__global__ __launch_bounds__(256) void vtrans(
    const u16* __restrict__ src, u16* __restrict__ dst)
{
    __shared__ u16 tile[64][65];
    const int bh = blockIdx.y;
    const int l0 = blockIdx.x * 64;
    const int tid = threadIdx.x;
    const u16* s = src + (long long)bh * 65536;
    u16* d = dst + (long long)bh * 65536;
    #pragma unroll
    for (int c = 0; c < 2; ++c) {
        int f = tid + c * 256;
        int r = f >> 3, cs = (f & 7) * 8;
        bf16x8 v = *(const bf16x8*)&s[(l0 + r) * 64 + cs];
        #pragma unroll
        for (int e = 0; e < 8; ++e) tile[r][cs + e] = (u16)v[e];
    }
    __syncthreads();
    int dl = tid >> 2, ls = (tid & 3) * 16;
    u16 outv[16];
    #pragma unroll
    for (int c = 0; c < 16; ++c) outv[c] = tile[ls + c][dl];
    *(bf16x8*)&d[dl * 1024 + l0 + ls]     = *(bf16x8*)&outv[0];
    *(bf16x8*)&d[dl * 1024 + l0 + ls + 8] = *(bf16x8*)&outv[8];
}

// ---------------------------------------------------------------------------
// RoPE + split qkv(B,L,3,H,D) bf16 -> q,k,v (B,H,L,D) bf16
// ---------------------------------------------------------------------------
__global__ __launch_bounds__(256) void rope_split_bf(
    const u16* __restrict__ qkv,
    u16* __restrict__ q, u16* __restrict__ k, u16* __restrict__ v)
{
    int idx = blockIdx.x * 256 + threadIdx.x;
    int d = idx & 63;
    int l = (idx >> 6) & 1023;
    int h = (idx >> 16) & 15;
    int b = idx >> 20;
    const long long src = ((long long)(b * Lv + l) * 3) * 1024 + h * 64 + d;
    int i = d & 31;
    float inv_freq = __expf((float)i * -0.28782313662425574f); // -ln(10000)/32
    float arg = (float)l * inv_freq;
    float c, s;
    __sincosf(arg, &s, &c);
    float x0 = b2f(qkv[src]);
    float xr0 = (d < 32) ? -b2f(qkv[src + 32]) : b2f(qkv[src - 32]);
    q[idx] = f2b(x0 * c + xr0 * s);
    float x1 = b2f(qkv[src + 1024]);
    float xr1 = (d < 32) ? -b2f(qkv[src + 1024 + 32]) : b2f(qkv[src + 1024 - 32]);
    k[idx] = f2b(x1 * c + xr1 * s);
    v[idx] = qkv[src + 2048];
}

// ---------------------------------------------------------------------------
// FUSED kerple + DAPE MLP (MFMA) + causal softmax, in-place on bf16 scores.
// One block of 512 threads (8 waves) per (b, i): 79.5 KB LDS -> 2 blocks/CU
// = 16 waves/CU (2x round-7 residency). Wave-autonomous softmax (2 heads per
// wave, shuffle reductions), coalesced weight writes + zero wedge.
// ---------------------------------------------------------------------------
#define LSTR 1044   // logits row stride (u16): mult of 4 for b64 alignment

__global__ __launch_bounds__(512) void dape_soft(
    u16* __restrict__ S, const u16* __restrict__ ktab,
    const float* __restrict__ w1, const float* __restrict__ b1,
    const float* __restrict__ w2, const float* __restrict__ b2)
{
    const int i = 1023 - blockIdx.x;         // longest rows first
    const int b = blockIdx.y;

    __shared__ u16 logits[16 * LSTR];        // 33.4 KB
    __shared__ u16 comb[512 * 36];           // 36.9 KB
    __shared__ u16 hid[8][16 * 36];          // 9.2 KB

    const int tid = threadIdx.x;
    const int lane = tid & 63;
    const int wave = tid >> 6;
    const int fr = lane & 15;
    const int fq = lane >> 4;

    // weight fragments (registers); B[n=lane&15][k=fq*8+e]
    bf16x8 B1a, B1b, B2f;
    #pragma unroll
    for (int e = 0; e < 8; ++e) {
        int c = fq * 8 + e;
        B1a[e] = (short)f2b(w1[c * 32 + fr]);
        B1b[e] = (short)f2b(w1[c * 32 + 16 + fr]);
        B2f[e] = (short)f2b(w2[c * 16 + fr]);
    }
    const float b1a = b1[fr], b1b = b1[16 + fr], b2v = b2[fr];

    const long long sbase = (long long)b * 16 * 1048576 + (long long)i * 1024;
    const int nchunk = (i >> 9) + 1;         // chunks of 512 positions

    for (int c = 0; c < nchunk; ++c) {
        const int j = c * 512 + tid;         // < 1024
        {   // stage comb[j][0..31]
            u16 row[32];
            #pragma unroll
            for (int h = 0; h < 16; ++h)
                row[h] = S[sbase + (long long)h * 1048576 + j];
            const int dist = (i - j > 0) ? (i - j) : 0;
            *(bf16x8*)&row[16] = *(const bf16x8*)&ktab[dist * 16];
            *(bf16x8*)&row[24] = *(const bf16x8*)&ktab[dist * 16 + 8];
            #pragma unroll
            for (int q = 0; q < 4; ++q)
                *(bf16x8*)&comb[tid * 36 + q * 8] = *(bf16x8*)&row[q * 8];
        }
        __syncthreads();

        for (int t = wave; t < 32; t += 8) {
            const int jt = c * 512 + t * 16;
            if (jt > i) continue;

            bf16x8 A1 = *(const bf16x8*)&comb[(t * 16 + fr) * 36 + fq * 8];
            f32x4 z = (f32x4){0.f, 0.f, 0.f, 0.f};
            f32x4 ac1a = __builtin_amdgcn_mfma_f32_16x16x32_bf16(A1, B1a, z, 0, 0, 0);
            f32x4 ac1b = __builtin_amdgcn_mfma_f32_16x16x32_bf16(A1, B1b, z, 0, 0, 0);

            #pragma unroll
            for (int r = 0; r < 4; ++r) {
                float g0 = gelu_fast(ac1a[r] + b1a);
                float g1 = gelu_fast(ac1b[r] + b1b);
                hid[wave][(fq * 4 + r) * 36 + fr]      = f2b(g0);
                hid[wave][(fq * 4 + r) * 36 + 16 + fr] = f2b(g1);
            }
            bf16x8 A2 = *(const bf16x8*)&hid[wave][fr * 36 + fq * 8];
            f32x4 ac2 = __builtin_amdgcn_mfma_f32_16x16x32_bf16(A2, B2f, z, 0, 0, 0);

            #pragma unroll
            for (int r = 0; r < 4; ++r) {
                int jl = t * 16 + fq * 4 + r;
                float scv = b2f(comb[jl * 36 + fr]);
                float kv  = b2f(comb[jl * 36 + 16 + fr]);
                logits[fr * LSTR + jt + fq * 4 + r] = f2b(scv + kv + ac2[r] + b2v);
            }
        }
        __syncthreads();                     // comb reuse + logits complete
    }

    // ---- wave-autonomous softmax: wave handles heads {wave, wave+8} ----
    const int we = ((i >> 7) + 1) << 7;      // PV K bound (zero wedge end)
    for (int hh = wave; hh < 16; hh += 8) {
        float vals[16];
        float mx = -3.0e38f;
        #pragma unroll
        for (int s = 0; s < 4; ++s) {
            u16x4 r4 = *(const u16x4*)&logits[hh * LSTR + lane * 4 + 256 * s];
            #pragma unroll
            for (int e = 0; e < 4; ++e) {
                int j = lane * 4 + 256 * s + e;
                float v = (j <= i) ? b2f(r4[e]) : -3.0e38f;
                vals[s * 4 + e] = v;
                mx = fmaxf(mx, v);
            }
        }
        #pragma unroll
        for (int off = 1; off < 64; off <<= 1)
            mx = fmaxf(mx, __shfl_xor(mx, off));
        float sm = 0.f;
        #pragma unroll
        for (int e = 0; e < 16; ++e) {
            float ev = (vals[e] > -1.0e37f) ? __expf(vals[e] - mx) : 0.f;
            vals[e] = ev;
            sm += ev;
        }
        #pragma unroll
        for (int off = 1; off < 64; off <<= 1)
            sm += __shfl_xor(sm, off);
        const float inv = 1.0f / sm;
        const long long hb = sbase + (long long)hh * 1048576;
        #pragma unroll
        for (int s = 0; s < 4; ++s) {
            int j0v = lane * 4 + 256 * s;
            if (j0v < we) {
                u16 o[4];
                #pragma unroll
                for (int e = 0; e < 4; ++e) o[e] = f2b(vals[s * 4 + e] * inv);
                *(u16x4*)&S[hb + j0v] = *(u16x4*)o;
            }
        }
    }
}

// ---------------------------------------------------------------------------
extern "C" void kernel_launch(void* const* d_in, const int* in_sizes, int n_in,
                              void* d_out, int out_size, void* d_ws, size_t ws_size,
                              hipStream_t stream)
{
    const float* x     = (const float*)d_in[0];
    const float* w_qkv = (const float*)d_in[1];
    const float* w_o   = (const float*)d_in[2];
    const float* log_p = (const float*)d_in[3];
    const float* log_a = (const float*)d_in[4];
    const float* w1    = (const float*)d_in[5];
    const float* b1    = (const float*)d_in[6];
    const float* w2    = (const float*)d_in[7];
    const float* b2    = (const float*)d_in[8];
    float* out = (float*)d_out;

    char* p = (char*)d_ws;
    u16* qkv_bf  = (u16*)p;    p += 6291456ll * 2;   // (B,L,3,H,D) bf16
    u16* x_bf    = (u16*)p;    p += 2097152ll * 2;
    u16* wqkvT   = (u16*)p;    p += 3145728ll * 2;   // (3HD, HID)
    u16* woT     = (u16*)p;    p += 1048576ll * 2;   // (HID, HD)
    u16* q_bf    = (u16*)p;    p += 2097152ll * 2;   // (B,H,L,D)
    u16* k_bf    = (u16*)p;    p += 2097152ll * 2;
    u16* v_bf    = (u16*)p;    p += 2097152ll * 2;
    u16* vT      = (u16*)p;    p += 2097152ll * 2;   // (B,H,D,L)
    u16* scores  = (u16*)p;    p += 33554432ll * 2;  // (B,H,L,L) bf16, in-place
    u16* attn_bf = (u16*)p;    p += 2097152ll * 2;   // (B,L,H*D)
    u16* ktab    = (u16*)p;    p += 16384ll * 2;     // kerple[dist][h]

    // casts / transposes / tables
    cast_f2b<<<8192, 256, 0, stream>>>(x, x_bf, 2097152);
    transpose_cast_f2b<<<dim3(48, 16), 256, 0, stream>>>(w_qkv, wqkvT, HIDv, 3 * Hv * Dv);
    transpose_cast_f2b<<<dim3(16, 16), 256, 0, stream>>>(w_o, woT, Hv * Dv, HIDv);
    kerple_tab<<<64, 256, 0, stream>>>(log_p, log_a, ktab);

    // 1. qkv = x @ w_qkv (bf16 out)
    gemm_bt<128, 128, 64, 64, true><<<dim3(24, 16, 1), 256, 0, stream>>>(
        x_bf, wqkvT, qkv_bf, 2048, 3072, 1024, 1.0f);

    // 2. rope + split
    rope_split_bf<<<8192, 256, 0, stream>>>(qkv_bf, q_bf, k_bf, v_bf);
    vtrans<<<dim3(16, 32), 256, 0, stream>>>(v_bf, vT);

    // 3. scores = (q @ k^T)/8, direct-from-global, causal tiles only
    qk_direct<<<dim3(8, 8, 32), 256, 0, stream>>>(q_bf, k_bf, scores);

    // 4. FUSED kerple + DAPE MLP + softmax (512 threads, 2 blocks/CU)
    dape_soft<<<dim3(1024, 2), 512, 0, stream>>>(
        scores, ktab, w1, b1, w2, b2);

    // 5. attn_bf = weights @ v, direct-from-global, triangular K
    pv_direct<<<dim3(16, 32), 256, 0, stream>>>(scores, vT, attn_bf);

    // 6. out = attn_fl @ w_o  (2048 x 1024 x 1024), 256 blocks
    gemm_bt<128, 64, 64, 32, false><<<dim3(16, 16, 1), 256, 0, stream>>>(
        attn_bf, woT, out, 2048, 1024, 1024, 1.0f);
}

// Round 9
// 237.856 us; speedup vs baseline: 11.7095x; 1.0918x over previous
//
#include <hip/hip_runtime.h>
#include <math.h>

#define Bv 2
#define Lv 1024
#define Hv 16
#define Dv 64
#define HIDv 1024

typedef unsigned short u16;
typedef short bf16x8 __attribute__((ext_vector_type(8)));
typedef unsigned short u16x4 __attribute__((ext_vector_type(4)));
typedef float f32x4 __attribute__((ext_vector_type(4)));

__device__ __forceinline__ u16 f2b(float f) {
    union { float f; unsigned u; } v; v.f = f;
    unsigned r = v.u + 0x7fffu + ((v.u >> 16) & 1u);
    return (u16)(r >> 16);
}
__device__ __forceinline__ float b2f(u16 h) {
    union { unsigned u; float f; } v; v.u = ((unsigned)h) << 16;
    return v.f;
}

// async global->LDS, 16B per lane (wave-uniform base + lane*16 order).
__device__ __forceinline__ void gl2lds16(const u16* g, u16* l) {
    __builtin_amdgcn_global_load_lds(
        (const __attribute__((address_space(1))) unsigned int*)g,
        (__attribute__((address_space(3))) unsigned int*)l,
        16, 0, 0);
}

// gelu with A&S 7.1.26 erf (max abs err 1.5e-7).
__device__ __forceinline__ float gelu_fast(float x) {
    float y = x * 0.70710678118654752f;
    float a = fabsf(y);
    float t = 1.0f / (1.0f + 0.3275911f * a);
    float p = t * (0.254829592f + t * (-0.284496736f +
              t * (1.421413741f + t * (-1.453152027f + t * 1.061405429f))));
    float e = __expf(-a * a);
    float erfv = copysignf(1.0f - p * e, y);
    return 0.5f * x * (1.0f + erfv);
}

// ---------------------------------------------------------------------------
// bf16 MFMA GEMM with global_load_lds staging: C = alpha * A @ B^T
// LDS tiles contiguous [rows][32] u16 (64B rows), matching lane*16 order.
// ---------------------------------------------------------------------------
template<int BM, int BN, int WM, int WN, bool CBF16>
__global__ __launch_bounds__(256) void gemm_bt(
    const u16* __restrict__ A, const u16* __restrict__ B, void* __restrict__ Cv,
    int M, int N, int K, float alpha)
{
    constexpr int NW = BN / WN;
    constexpr int MI = WM / 16;
    constexpr int NI = WN / 16;
    __shared__ u16 As[BM * 32];
    __shared__ u16 Bs[BN * 32];

    const int m0 = blockIdx.y * BM;
    const int n0 = blockIdx.x * BN;

    const int tid = threadIdx.x;
    const int lane = tid & 63;
    const int wave = tid >> 6;
    const int wm0 = (wave / NW) * WM;
    const int wn0 = (wave % NW) * WN;
    const int fr = lane & 15;
    const int fq = lane >> 4;

    f32x4 acc[MI][NI];
    #pragma unroll
    for (int i = 0; i < MI; ++i)
        #pragma unroll
        for (int j = 0; j < NI; ++j) acc[i][j] = (f32x4){0.f, 0.f, 0.f, 0.f};

    for (int k0 = 0; k0 < K; k0 += 32) {
        #pragma unroll
        for (int it = 0; it < BM / 64; ++it) {
            int cid = tid + it * 256;
            int r = cid >> 2, ch = cid & 3;
            gl2lds16(A + (long long)(m0 + r) * K + k0 + ch * 8, &As[cid * 8]);
        }
        #pragma unroll
        for (int it = 0; it < BN / 64; ++it) {
            int cid = tid + it * 256;
            int r = cid >> 2, ch = cid & 3;
            gl2lds16(B + (long long)(n0 + r) * K + k0 + ch * 8, &Bs[cid * 8]);
        }
        __syncthreads();
        bf16x8 af[MI], bfr[NI];
        #pragma unroll
        for (int i = 0; i < MI; ++i)
            af[i] = *(const bf16x8*)&As[(wm0 + i * 16 + fr) * 32 + fq * 8];
        #pragma unroll
        for (int j = 0; j < NI; ++j)
            bfr[j] = *(const bf16x8*)&Bs[(wn0 + j * 16 + fr) * 32 + fq * 8];
        #pragma unroll
        for (int i = 0; i < MI; ++i)
            #pragma unroll
            for (int j = 0; j < NI; ++j)
                acc[i][j] = __builtin_amdgcn_mfma_f32_16x16x32_bf16(
                    af[i], bfr[j], acc[i][j], 0, 0, 0);
        __syncthreads();
    }

    #pragma unroll
    for (int i = 0; i < MI; ++i)
        #pragma unroll
        for (int j = 0; j < NI; ++j)
            #pragma unroll
            for (int r = 0; r < 4; ++r) {
                int row = m0 + wm0 + i * 16 + fq * 4 + r;
                int col = n0 + wn0 + j * 16 + fr;
                float v = acc[i][j][r] * alpha;
                if (CBF16) ((u16*)Cv)[(long long)row * N + col] = f2b(v);
                else      ((float*)Cv)[(long long)row * N + col] = v;
            }
}

// ---------------------------------------------------------------------------
// QK^T direct-from-global (K=64 in fragments; no LDS, no barriers).
// grid (8, 8, B*H); 128x128 tile, 4 waves of 64x64.
// ---------------------------------------------------------------------------
__global__ __launch_bounds__(256) void qk_direct(
    const u16* __restrict__ Q, const u16* __restrict__ K, u16* __restrict__ S)
{
    const int m0 = blockIdx.y * 128;
    const int n0 = blockIdx.x * 128;
    if (n0 > m0) return;
    const u16* A = Q + (long long)blockIdx.z * 65536;
    const u16* B = K + (long long)blockIdx.z * 65536;
    u16* C = S + (long long)blockIdx.z * 1048576;

    const int lane = threadIdx.x & 63;
    const int wave = threadIdx.x >> 6;
    const int wm0 = (wave >> 1) * 64;
    const int wn0 = (wave & 1) * 64;
    const int fr = lane & 15;
    const int fq = lane >> 4;

    bf16x8 af[4][2], bfr[4][2];
    #pragma unroll
    for (int i = 0; i < 4; ++i)
        #pragma unroll
        for (int p = 0; p < 2; ++p) {
            af[i][p]  = *(const bf16x8*)&A[(m0 + wm0 + i * 16 + fr) * 64 + p * 32 + fq * 8];
            bfr[i][p] = *(const bf16x8*)&B[(n0 + wn0 + i * 16 + fr) * 64 + p * 32 + fq * 8];
        }

    f32x4 acc[4][4];
    #pragma unroll
    for (int i = 0; i < 4; ++i)
        #pragma unroll
        for (int j = 0; j < 4; ++j) acc[i][j] = (f32x4){0.f, 0.f, 0.f, 0.f};

    #pragma unroll
    for (int p = 0; p < 2; ++p)
        #pragma unroll
        for (int i = 0; i < 4; ++i)
            #pragma unroll
            for (int j = 0; j < 4; ++j)
                acc[i][j] = __builtin_amdgcn_mfma_f32_16x16x32_bf16(
                    af[i][p], bfr[j][p], acc[i][j], 0, 0, 0);

    #pragma unroll
    for (int i = 0; i < 4; ++i)
        #pragma unroll
        for (int j = 0; j < 4; ++j)
            #pragma unroll
            for (int r = 0; r < 4; ++r) {
                int row = m0 + wm0 + i * 16 + fq * 4 + r;
                int col = n0 + wn0 + j * 16 + fr;
                C[(long long)row * 1024 + col] = f2b(acc[i][j][r] * 0.125f);
            }
}

// ---------------------------------------------------------------------------
// PV direct-from-global (triangular K, no LDS, no barriers).
// grid (16, B*H); writes bf16 into (B,L,H*D).
// ---------------------------------------------------------------------------
__global__ __launch_bounds__(256) void pv_direct(
    const u16* __restrict__ W, const u16* __restrict__ VT, u16* __restrict__ O)
{
    const int m0 = blockIdx.x * 64;
    const int bh = blockIdx.y;
    const u16* A = W + (long long)bh * 1048576;
    const u16* B = VT + (long long)bh * 65536;
    const int b = bh >> 4, h = bh & 15;

    const int lane = threadIdx.x & 63;
    const int wave = threadIdx.x >> 6;
    const int wm0 = (wave >> 1) * 32;
    const int wn0 = (wave & 1) * 32;
    const int fr = lane & 15;
    const int fq = lane >> 4;

    f32x4 acc[2][2];
    #pragma unroll
    for (int i = 0; i < 2; ++i)
        #pragma unroll
        for (int j = 0; j < 2; ++j) acc[i][j] = (f32x4){0.f, 0.f, 0.f, 0.f};

    const int Kend = m0 + 64;
    for (int k0 = 0; k0 < Kend; k0 += 64) {
        bf16x8 af[2][2], bfr[2][2];
        #pragma unroll
        for (int p = 0; p < 2; ++p) {
            #pragma unroll
            for (int i = 0; i < 2; ++i)
                af[p][i] = *(const bf16x8*)&A[(m0 + wm0 + i * 16 + fr) * 1024 + k0 + p * 32 + fq * 8];
            #pragma unroll
            for (int j = 0; j < 2; ++j)
                bfr[p][j] = *(const bf16x8*)&B[(wn0 + j * 16 + fr) * 1024 + k0 + p * 32 + fq * 8];
        }
        #pragma unroll
        for (int p = 0; p < 2; ++p)
            #pragma unroll
            for (int i = 0; i < 2; ++i)
                #pragma unroll
                for (int j = 0; j < 2; ++j)
                    acc[i][j] = __builtin_amdgcn_mfma_f32_16x16x32_bf16(
                        af[p][i], bfr[p][j], acc[i][j], 0, 0, 0);
    }

    const long long ob = (long long)b * 1048576 + h * 64;
    #pragma unroll
    for (int i = 0; i < 2; ++i)
        #pragma unroll
        for (int j = 0; j < 2; ++j)
            #pragma unroll
            for (int r = 0; r < 4; ++r) {
                int row = m0 + wm0 + i * 16 + fq * 4 + r;
                int col = wn0 + j * 16 + fr;
                O[ob + (long long)row * 1024 + col] = f2b(acc[i][j][r]);
            }
}

// ---------------------------------------------------------------------------
// Fused prep: cast x (blocks 0..8191), transpose wqkv (..8959),
// transpose wo (..9215), kerple table (..9279).
// ---------------------------------------------------------------------------
__global__ __launch_bounds__(256) void prep(
    const float* __restrict__ x, u16* __restrict__ x_bf,
    const float* __restrict__ w_qkv, u16* __restrict__ wqkvT,
    const float* __restrict__ w_o, u16* __restrict__ woT,
    const float* __restrict__ log_p, const float* __restrict__ log_a,
    u16* __restrict__ ktab)
{
    __shared__ float tile[64][65];
    const int bid = blockIdx.x;
    const int tid = threadIdx.x;

    if (bid < 8192) {
        int i = bid * 256 + tid;
        x_bf[i] = f2b(x[i]);
        return;
    }
    if (bid >= 9216) {
        int idx = (bid - 9216) * 256 + tid;    // 16384
        int h = idx & 15, dist = idx >> 4;
        float pp = log1pf(__expf(log_p[h]));
        float aa = log1pf(__expf(log_a[h]));
        ktab[idx] = f2b(-pp * log1pf(aa * (float)dist));
        return;
    }
    const float* src; u16* dst; int M, N, bx, by;
    if (bid < 8960) { int t = bid - 8192; bx = t % 48; by = t / 48; src = w_qkv; dst = wqkvT; M = 1024; N = 3072; }
    else            { int t = bid - 8960; bx = t % 16; by = t / 16; src = w_o;   dst = woT;   M = 1024; N = 1024; }
    const int m0 = by * 64, n0 = bx * 64;
    #pragma unroll
    for (int c = 0; c < 4; ++c) {
        int f = tid + c * 256;
        int r = f >> 4, cs = (f & 15) * 4;
        float4 v = *(const float4*)&src[(long long)(m0 + r) * N + n0 + cs];
        tile[r][cs] = v.x; tile[r][cs + 1] = v.y;
        tile[r][cs + 2] = v.z; tile[r][cs + 3] = v.w;
    }
    __syncthreads();
    int nl = tid >> 2, ms = (tid & 3) * 16;
    u16 outv[16];
    #pragma unroll
    for (int c = 0; c < 16; ++c) outv[c] = f2b(tile[ms + c][nl]);
    *(bf16x8*)&dst[(long long)(n0 + nl) * M + m0 + ms]     = *(bf16x8*)&outv[0];
    *(bf16x8*)&dst[(long long)(n0 + nl) * M + m0 + ms + 8] = *(bf16x8*)&outv[8];
}

// ---------------------------------------------------------------------------
// Fused RoPE + split + V-transpose. grid (L/64, B*H), 256 threads.
// Reads qkv(B,L,3,H,D) bf16; writes q,k (B,H,L,D) and vT (B,H,D,L).
// ---------------------------------------------------------------------------
__global__ __launch_bounds__(256) void rope_vt(
    const u16* __restrict__ qkv,
    u16* __restrict__ q, u16* __restrict__ k, u16* __restrict__ vT)
{
    __shared__ u16 tile[64][65];
    const int l0 = blockIdx.x * 64;
    const int bh = blockIdx.y;
    const int b = bh >> 4, h = bh & 15;
    const int tid = threadIdx.x;
    const int r = tid >> 2;            // l offset in tile
    const int cs = (tid & 3) * 16;     // d start
    const int l = l0 + r;
    const long long src = ((long long)(b * 1024 + l) * 3) * 1024 + h * 64;
    const long long qkbase = ((long long)bh * 1024 + l) * 64 + cs;

    // sincos shared between q and k
    float cv[16], sv[16];
    #pragma unroll
    for (int e = 0; e < 16; ++e) {
        int d = cs + e;
        float inv_freq = __expf((float)(d & 31) * -0.28782313662425574f);
        __sincosf((float)l * inv_freq, &sv[e], &cv[e]);
    }
    const int csp = cs ^ 32;
    const float sgn = (cs < 32) ? -1.0f : 1.0f;

    #pragma unroll
    for (int w = 0; w < 2; ++w) {      // w=0: q, w=1: k
        const long long s0 = src + w * 1024;
        u16 xv[16], xp[16];
        *(bf16x8*)&xv[0] = *(const bf16x8*)&qkv[s0 + cs];
        *(bf16x8*)&xv[8] = *(const bf16x8*)&qkv[s0 + cs + 8];
        *(bf16x8*)&xp[0] = *(const bf16x8*)&qkv[s0 + csp];
        *(bf16x8*)&xp[8] = *(const bf16x8*)&qkv[s0 + csp + 8];
        u16 o[16];
        #pragma unroll
        for (int e = 0; e < 16; ++e)
            o[e] = f2b(b2f(xv[e]) * cv[e] + sgn * b2f(xp[e]) * sv[e]);
        u16* dst = w ? k : q;
        *(bf16x8*)&dst[qkbase]     = *(bf16x8*)&o[0];
        *(bf16x8*)&dst[qkbase + 8] = *(bf16x8*)&o[8];
    }

    // v -> LDS -> transposed write
    *(bf16x8*)&tile[r][cs]     = *(const bf16x8*)&qkv[src + 2048 + cs];
    *(bf16x8*)&tile[r][cs + 8] = *(const bf16x8*)&qkv[src + 2048 + cs + 8];
    __syncthreads();
    int dl = tid >> 2, ls = (tid & 3) * 16;
    u16 outv[16];
    #pragma unroll
    for (int c = 0; c < 16; ++c) outv[c] = tile[ls + c][dl];
    u16* d = vT + (long long)bh * 65536 + dl * 1024 + l0 + ls;
    *(bf16x8*)&d[0] = *(bf16x8*)&outv[0];
    *(bf16x8*)&d[8] = *(bf16x8*)&outv[8];
}

// ---------------------------------------------------------------------------
// FUSED kerple + DAPE MLP (MFMA) + causal softmax, in-place on bf16 scores.
// 512 threads (8 waves) per (b, i). The score+kerple residual is folded into
// the layer-2 MFMA chain via a constant identity B-fragment (Bid), C init b2.
// ---------------------------------------------------------------------------
#define LSTR 1044   // logits row stride (u16), mult of 4

__global__ __launch_bounds__(512) void dape_soft(
    u16* __restrict__ S, const u16* __restrict__ ktab,
    const float* __restrict__ w1, const float* __restrict__ b1,
    const float* __restrict__ w2, const float* __restrict__ b2)
{
    const int i = 1023 - blockIdx.x;
    const int b = blockIdx.y;

    __shared__ u16 logits[16 * LSTR];
    __shared__ u16 comb[512 * 36];
    __shared__ u16 hid[8][16 * 36];

    const int tid = threadIdx.x;
    const int lane = tid & 63;
    const int wave = tid >> 6;
    const int fr = lane & 15;
    const int fq = lane >> 4;

    // weight fragments; B[n=fr][k=fq*8+e]
    bf16x8 B1a, B1b, B2f, Bid;
    #pragma unroll
    for (int e = 0; e < 8; ++e) {
        int c = fq * 8 + e;
        B1a[e] = (short)f2b(w1[c * 32 + fr]);
        B1b[e] = (short)f2b(w1[c * 32 + 16 + fr]);
        B2f[e] = (short)f2b(w2[c * 16 + fr]);
        Bid[e] = (short)((c == fr || c == 16 + fr) ? 0x3F80 : 0);  // bf16 1.0
    }
    const float b1a = b1[fr], b1b = b1[16 + fr], b2v = b2[fr];

    const long long sbase = (long long)b * 16 * 1048576 + (long long)i * 1024;
    const int nchunk = (i >> 9) + 1;

    for (int c = 0; c < nchunk; ++c) {
        const int j = c * 512 + tid;
        {   // stage comb[j][0..31]
            u16 row[32];
            #pragma unroll
            for (int h = 0; h < 16; ++h)
                row[h] = S[sbase + (long long)h * 1048576 + j];
            const int dist = (i - j > 0) ? (i - j) : 0;
            *(bf16x8*)&row[16] = *(const bf16x8*)&ktab[dist * 16];
            *(bf16x8*)&row[24] = *(const bf16x8*)&ktab[dist * 16 + 8];
            #pragma unroll
            for (int qq = 0; qq < 4; ++qq)
                *(bf16x8*)&comb[tid * 36 + qq * 8] = *(bf16x8*)&row[qq * 8];
        }
        __syncthreads();

        for (int t = wave; t < 32; t += 8) {
            const int jt = c * 512 + t * 16;
            if (jt > i) continue;

            bf16x8 A1 = *(const bf16x8*)&comb[(t * 16 + fr) * 36 + fq * 8];
            f32x4 z = (f32x4){0.f, 0.f, 0.f, 0.f};
            f32x4 ac1a = __builtin_amdgcn_mfma_f32_16x16x32_bf16(A1, B1a, z, 0, 0, 0);
            f32x4 ac1b = __builtin_amdgcn_mfma_f32_16x16x32_bf16(A1, B1b, z, 0, 0, 0);
            // residual (score + kerple + b2) via identity MFMA
            f32x4 cres = __builtin_amdgcn_mfma_f32_16x16x32_bf16(
                A1, Bid, (f32x4){b2v, b2v, b2v, b2v}, 0, 0, 0);

            #pragma unroll
            for (int r = 0; r < 4; ++r) {
                float g0 = gelu_fast(ac1a[r] + b1a);
                float g1 = gelu_fast(ac1b[r] + b1b);
                hid[wave][(fq * 4 + r) * 36 + fr]      = f2b(g0);
                hid[wave][(fq * 4 + r) * 36 + 16 + fr] = f2b(g1);
            }
            bf16x8 A2 = *(const bf16x8*)&hid[wave][fr * 36 + fq * 8];
            f32x4 ac2 = __builtin_amdgcn_mfma_f32_16x16x32_bf16(A2, B2f, cres, 0, 0, 0);

            u16 o[4];
            #pragma unroll
            for (int r = 0; r < 4; ++r) o[r] = f2b(ac2[r]);
            *(u16x4*)&logits[fr * LSTR + jt + fq * 4] = *(u16x4*)o;
        }
        __syncthreads();
    }

    // ---- wave-autonomous softmax: wave handles heads {wave, wave+8} ----
    const int we = ((i >> 7) + 1) << 7;
    for (int hh = wave; hh < 16; hh += 8) {
        float vals[16];
        float mx = -3.0e38f;
        #pragma unroll
        for (int s = 0; s < 4; ++s) {
            u16x4 r4 = *(const u16x4*)&logits[hh * LSTR + lane * 4 + 256 * s];
            #pragma unroll
            for (int e = 0; e < 4; ++e) {
                int j = lane * 4 + 256 * s + e;
                float v = (j <= i) ? b2f(r4[e]) : -3.0e38f;
                vals[s * 4 + e] = v;
                mx = fmaxf(mx, v);
            }
        }
        #pragma unroll
        for (int off = 1; off < 64; off <<= 1)
            mx = fmaxf(mx, __shfl_xor(mx, off));
        float sm = 0.f;
        #pragma unroll
        for (int e = 0; e < 16; ++e) {
            float ev = (vals[e] > -1.0e37f) ? __expf(vals[e] - mx) : 0.f;
            vals[e] = ev;
            sm += ev;
        }
        #pragma unroll
        for (int off = 1; off < 64; off <<= 1)
            sm += __shfl_xor(sm, off);
        const float inv = 1.0f / sm;
        const long long hb = sbase + (long long)hh * 1048576;
        #pragma unroll
        for (int s = 0; s < 4; ++s) {
            int j0v = lane * 4 + 256 * s;
            if (j0v < we) {
                u16 o[4];
                #pragma unroll
                for (int e = 0; e < 4; ++e) o[e] = f2b(vals[s * 4 + e] * inv);
                *(u16x4*)&S[hb + j0v] = *(u16x4*)o;
            }
        }
    }
}

// ---------------------------------------------------------------------------
extern "C" void kernel_launch(void* const* d_in, const int* in_sizes, int n_in,
                              void* d_out, int out_size, void* d_ws, size_t ws_size,
                              hipStream_t stream)
{
    const float* x     = (const float*)d_in[0];
    const float* w_qkv = (const float*)d_in[1];
    const float* w_o   = (const float*)d_in[2];
    const float* log_p = (const float*)d_in[3];
    const float* log_a = (const float*)d_in[4];
    const float* w1    = (const float*)d_in[5];
    const float* b1    = (const float*)d_in[6];
    const float* w2    = (const float*)d_in[7];
    const float* b2    = (const float*)d_in[8];
    float* out = (float*)d_out;

    char* p = (char*)d_ws;
    u16* qkv_bf  = (u16*)p;    p += 6291456ll * 2;   // (B,L,3,H,D) bf16
    u16* x_bf    = (u16*)p;    p += 2097152ll * 2;
    u16* wqkvT   = (u16*)p;    p += 3145728ll * 2;   // (3HD, HID)
    u16* woT     = (u16*)p;    p += 1048576ll * 2;   // (HID, HD)
    u16* q_bf    = (u16*)p;    p += 2097152ll * 2;   // (B,H,L,D)
    u16* k_bf    = (u16*)p;    p += 2097152ll * 2;
    u16* vT      = (u16*)p;    p += 2097152ll * 2;   // (B,H,D,L)
    u16* scores  = (u16*)p;    p += 33554432ll * 2;  // (B,H,L,L) bf16, in-place
    u16* attn_bf = (u16*)p;    p += 2097152ll * 2;   // (B,L,H*D)
    u16* ktab    = (u16*)p;    p += 16384ll * 2;     // kerple[dist][h]

    // 0. fused prep: cast x, transpose weights, kerple table
    prep<<<9280, 256, 0, stream>>>(x, x_bf, w_qkv, wqkvT, w_o, woT,
                                   log_p, log_a, ktab);

    // 1. qkv = x @ w_qkv (bf16 out), 64x128 tiles -> 768 blocks
    gemm_bt<64, 128, 32, 64, true><<<dim3(24, 32, 1), 256, 0, stream>>>(
        x_bf, wqkvT, qkv_bf, 2048, 3072, 1024, 1.0f);

    // 2. fused rope + split + v-transpose
    rope_vt<<<dim3(16, 32), 256, 0, stream>>>(qkv_bf, q_bf, k_bf, vT);

    // 3. scores = (q @ k^T)/8, direct-from-global, causal tiles only
    qk_direct<<<dim3(8, 8, 32), 256, 0, stream>>>(q_bf, k_bf, scores);

    // 4. FUSED kerple + DAPE MLP + softmax (512 threads, 2 blocks/CU)
    dape_soft<<<dim3(1024, 2), 512, 0, stream>>>(
        scores, ktab, w1, b1, w2, b2);

    // 5. attn_bf = weights @ v, direct-from-global, triangular K
    pv_direct<<<dim3(16, 32), 256, 0, stream>>>(scores, vT, attn_bf);

    // 6. out = attn_fl @ w_o, 64x64 tiles -> 512 blocks
    gemm_bt<64, 64, 32, 32, false><<<dim3(16, 32, 1), 256, 0, stream>>>(
        attn_bf, woT, out, 2048, 1024, 1024, 1.0f);
}